// Round 1
// baseline (1859.760 us; speedup 1.0000x reference)
//
#include <hip/hip_runtime.h>
#include <hip/hip_bf16.h>
#include <math.h>

#define HEADS 8
#define LL 4096
#define CDIM 256
#define BATCH 16
#define NROWS (BATCH*LL)

// ---------------------------------------------------------------------------
// pos table (4096 x 256) + cosFormer sin/cos table (4096 x 2)
// pos[l][c]: c<64: sin(y*om[c]); <128: cos(y*om[c-64]); <192: sin(x*om[..]); else cos(x*om[..])
// with y = l/64, x = l%64, om[k] = 10000^(-k/64)
__global__ void pos_kernel(float* __restrict__ pos, float* __restrict__ snc) {
    int l = blockIdx.x;
    int c = threadIdx.x;
    int y = l >> 6, x = l & 63;
    int k = c & 63;
    float omega = expf(-(float)k * (9.210340371976184f / 64.0f));  // ln(10000)/64
    float coord = (c < 128) ? (float)y : (float)x;
    float ang = coord * omega;
    float val = ((c & 127) < 64) ? sinf(ang) : cosf(ang);
    pos[l * CDIM + c] = val;
    if (c < 2) {
        float wi = 1.5707963267948966f * (float)(l + 1) / (float)LL;
        snc[l * 2 + c] = (c == 0) ? sinf(wi) : cosf(wi);
    }
}

// ---------------------------------------------------------------------------
// a3 (b,256,128,128) --avgpool2--> residual (b,L,256), x3 = residual + pos
__global__ __launch_bounds__(256) void pool_x3_kernel(
    const float* __restrict__ a3, float* __restrict__ residual,
    float* __restrict__ x3, const float* __restrict__ pos)
{
    __shared__ float raw[64][128];     // sum of the two source rows, per cc
    __shared__ float pooled[64][65];   // pooled tile, padded
    int i = blockIdx.x;    // pooled row 0..63
    int ct = blockIdx.y;   // channel tile 0..3
    int b = blockIdx.z;
    int tid = threadIdx.x;
    // phase 1: load rows 2i and 2i+1 for 64 channels, sum them
    #pragma unroll
    for (int it = 0; it < 8; ++it) {
        int lin = (it * 256 + tid) * 4;      // 0..8191 step 4
        int x = lin & 127;
        int cc = lin >> 7;
        size_t base = ((size_t)(b * 256 + ct * 64 + cc) * 128 + 2 * i) * 128 + x;
        float4 v0 = *(const float4*)&a3[base];
        float4 v1 = *(const float4*)&a3[base + 128];
        float4 s = make_float4(v0.x + v1.x, v0.y + v1.y, v0.z + v1.z, v0.w + v1.w);
        *(float4*)&raw[cc][x] = s;
    }
    __syncthreads();
    // phase 2: horizontal pool
    #pragma unroll
    for (int it = 0; it < 16; ++it) {
        int idx = it * 256 + tid;
        int j = idx & 63, cc = idx >> 6;
        pooled[cc][j] = 0.25f * (raw[cc][2 * j] + raw[cc][2 * j + 1]);
    }
    __syncthreads();
    // phase 3: write (b,l,c) coalesced over c
    #pragma unroll
    for (int it = 0; it < 16; ++it) {
        int cc = tid & 63;
        int jj = (tid >> 6) + it * 4;
        float val = pooled[cc][jj];
        int l = i * 64 + jj;
        int c = ct * 64 + cc;
        size_t o = (size_t)(b * LL + l) * CDIM + c;
        residual[o] = val;
        x3[o] = val + pos[l * CDIM + c];
    }
}

// ---------------------------------------------------------------------------
// a4 (b,256,64,64) --transpose--> x4 (b,L,256) + pos
__global__ __launch_bounds__(256) void x4_kernel(
    const float* __restrict__ a4, float* __restrict__ x4, const float* __restrict__ pos)
{
    __shared__ float t2[64][65];
    int y = blockIdx.x, ct = blockIdx.y, b = blockIdx.z, tid = threadIdx.x;
    #pragma unroll
    for (int it = 0; it < 16; ++it) {
        int idx = it * 256 + tid;
        int x = idx & 63, cc = idx >> 6;
        t2[cc][x] = a4[((size_t)(b * 256 + ct * 64 + cc) * 64 + y) * 64 + x];
    }
    __syncthreads();
    #pragma unroll
    for (int it = 0; it < 16; ++it) {
        int cc = tid & 63;
        int xx = (tid >> 6) + it * 4;
        int l = y * 64 + xx, c = ct * 64 + cc;
        x4[(size_t)(b * LL + l) * CDIM + c] = t2[cc][xx] + pos[l * CDIM + c];
    }
}

// ---------------------------------------------------------------------------
// Fused GEMM: out = epilogue(X @ W + bias)
// X: N x K, W: K x colsTot. Tile 32 rows x 256 cols. Block 256 threads.
// Wave w owns rows r0=w*8..w*8+7 and all 256 cols -> LN = 64-lane shuffle reduce.
template<bool DO_LN, bool DO_RELU, bool DO_GELU, bool DO_RES>
__global__ __launch_bounds__(256) void gemm_fused(
    const float* __restrict__ X, const float* __restrict__ W,
    const float* __restrict__ bias, const float* __restrict__ g,
    const float* __restrict__ beta, const float* __restrict__ res,
    float* __restrict__ out, int K, int colsTot)
{
    __shared__ float As[32][32];    // [kk][row]
    __shared__ float Bs[32][256];   // [kk][col]
    int tid = threadIdx.x;
    int row0 = blockIdx.x * 32;
    int cb = blockIdx.y * 256;
    int c0 = (tid & 63) * 4;
    int r0 = (tid >> 6) * 8;
    int ar = tid >> 3;           // 0..31
    int ak = (tid & 7) * 4;      // 0,4,..,28
    int bc = (tid & 63) * 4;
    int bk = tid >> 6;           // 0..3
    float acc[8][4] = {};

    for (int kb = 0; kb < K; kb += 32) {
        float4 av = *(const float4*)&X[(size_t)(row0 + ar) * K + kb + ak];
        As[ak + 0][ar] = av.x; As[ak + 1][ar] = av.y;
        As[ak + 2][ar] = av.z; As[ak + 3][ar] = av.w;
        #pragma unroll
        for (int it = 0; it < 8; ++it) {
            int kk = it * 4 + bk;
            *(float4*)&Bs[kk][bc] =
                *(const float4*)&W[(size_t)(kb + kk) * colsTot + cb + bc];
        }
        __syncthreads();
        #pragma unroll
        for (int kk = 0; kk < 32; ++kk) {
            float4 b4 = *(float4*)&Bs[kk][c0];
            float4 a0 = *(float4*)&As[kk][r0];
            float4 a1 = *(float4*)&As[kk][r0 + 4];
            float ar8[8] = {a0.x, a0.y, a0.z, a0.w, a1.x, a1.y, a1.z, a1.w};
            #pragma unroll
            for (int i2 = 0; i2 < 8; ++i2) {
                acc[i2][0] += ar8[i2] * b4.x;
                acc[i2][1] += ar8[i2] * b4.y;
                acc[i2][2] += ar8[i2] * b4.z;
                acc[i2][3] += ar8[i2] * b4.w;
            }
        }
        __syncthreads();
    }

    int cbase = cb + c0;
    float4 bias4 = *(const float4*)&bias[cbase];
    #pragma unroll
    for (int i = 0; i < 8; ++i) {
        acc[i][0] += bias4.x; acc[i][1] += bias4.y;
        acc[i][2] += bias4.z; acc[i][3] += bias4.w;
    }
    if constexpr (DO_LN) {
        float4 g4 = *(const float4*)&g[cbase];
        float4 be4 = *(const float4*)&beta[cbase];
        float gg[4] = {g4.x, g4.y, g4.z, g4.w};
        float bb[4] = {be4.x, be4.y, be4.z, be4.w};
        #pragma unroll
        for (int i = 0; i < 8; ++i) {
            float s = acc[i][0] + acc[i][1] + acc[i][2] + acc[i][3];
            float ss = acc[i][0]*acc[i][0] + acc[i][1]*acc[i][1]
                     + acc[i][2]*acc[i][2] + acc[i][3]*acc[i][3];
            #pragma unroll
            for (int msk = 32; msk >= 1; msk >>= 1) {
                s += __shfl_xor(s, msk, 64);
                ss += __shfl_xor(ss, msk, 64);
            }
            float mu = s * (1.0f / 256.0f);
            float var = ss * (1.0f / 256.0f) - mu * mu;
            float rstd = rsqrtf(var + 1e-5f);
            #pragma unroll
            for (int j = 0; j < 4; ++j)
                acc[i][j] = (acc[i][j] - mu) * rstd * gg[j] + bb[j];
        }
    }
    if constexpr (DO_RELU) {
        #pragma unroll
        for (int i = 0; i < 8; ++i)
            #pragma unroll
            for (int j = 0; j < 4; ++j)
                acc[i][j] = fmaxf(acc[i][j], 0.0f);
    }
    if constexpr (DO_GELU) {
        #pragma unroll
        for (int i = 0; i < 8; ++i)
            #pragma unroll
            for (int j = 0; j < 4; ++j) {
                float v = acc[i][j];
                acc[i][j] = 0.5f * v * (1.0f + erff(v * 0.7071067811865476f));
            }
    }
    #pragma unroll
    for (int i = 0; i < 8; ++i) {
        size_t orow = (size_t)(row0 + r0 + i) * colsTot + cbase;
        float4 v = make_float4(acc[i][0], acc[i][1], acc[i][2], acc[i][3]);
        if constexpr (DO_RES) {
            float4 r4 = *(const float4*)&res[orow];
            v.x += r4.x; v.y += r4.y; v.z += r4.z; v.w += r4.w;
        }
        *(float4*)&out[orow] = v;
    }
}

// ---------------------------------------------------------------------------
// cosFormer stage 1: per (b,h,chunk): partial KVs/KVc (32x32) and sn/cs-weighted Ksum (32)
// KVs[d][m] = sum_l sn[l]*K[l,d]*V[l,m], KVc with cs. Partial layout per (bh,chunk):
// [0..1023]=KVs, [1024..2047]=KVc, [2048..2079]=Ksum_s, [2080..2111]=Ksum_c
__global__ __launch_bounds__(256) void kv_kernel(
    const float* __restrict__ Kmat, const float* __restrict__ Vmat,
    const float* __restrict__ snc, float* __restrict__ kvpart)
{
    __shared__ float Kt[64][32];
    __shared__ float Vt[64][32];
    __shared__ float sns[64], css[64];
    int chunk = blockIdx.x;   // 0..7
    int bh = blockIdx.y;      // 0..127
    int b = bh >> 3, h = bh & 7;
    int tid = threadIdx.x;
    int m = tid & 31;
    int d0 = (tid >> 5) * 4;
    float accs[4] = {}, accc[4] = {};
    float kss[4] = {}, ksc[4] = {};
    int l0chunk = chunk * 512;
    for (int sub = 0; sub < 8; ++sub) {
        int l0 = l0chunk + sub * 64;
        int ltb = tid >> 5;
        int col = tid & 31;
        #pragma unroll
        for (int it = 0; it < 8; ++it) {
            int ll = ltb + it * 8;
            size_t base = (size_t)(b * LL + l0 + ll) * CDIM + h * 32 + col;
            Kt[ll][col] = Kmat[base];
            Vt[ll][col] = Vmat[base];
        }
        if (tid < 64) { sns[tid] = snc[(l0 + tid) * 2]; css[tid] = snc[(l0 + tid) * 2 + 1]; }
        __syncthreads();
        for (int lt = 0; lt < 64; ++lt) {
            float s = sns[lt], c = css[lt];
            float v = Vt[lt][m];
            #pragma unroll
            for (int i2 = 0; i2 < 4; ++i2) {
                float kd = Kt[lt][d0 + i2];
                float t1 = kd * v;
                accs[i2] += t1 * s;
                accc[i2] += t1 * c;
                kss[i2] += kd * s;   // duplicated across m-lanes; only m==0 writes
                ksc[i2] += kd * c;
            }
        }
        __syncthreads();
    }
    size_t base = (size_t)(bh * 8 + chunk) * 2112;
    #pragma unroll
    for (int i2 = 0; i2 < 4; ++i2) {
        kvpart[base + (d0 + i2) * 32 + m] = accs[i2];
        kvpart[base + 1024 + (d0 + i2) * 32 + m] = accc[i2];
        if (m == 0) {
            kvpart[base + 2048 + d0 + i2] = kss[i2];
            kvpart[base + 2080 + d0 + i2] = ksc[i2];
        }
    }
}

// ---------------------------------------------------------------------------
// cosFormer stage 2: attn[l, h*32+m] = Z * (sn*Q.KVs[:,m] + cs*Q.KVc[:,m])
// Z = 1/max(sn*Q.Ksum_s + cs*Q.Ksum_c, 1e-6)
__global__ __launch_bounds__(256) void attn_kernel(
    const float* __restrict__ Qmat, const float* __restrict__ kvpart,
    const float* __restrict__ snc, float* __restrict__ attnOut)
{
    __shared__ float lds[16896];   // 8 heads x 2112
    int ltile = blockIdx.x;        // 0..63
    int b = blockIdx.y;
    int tid = threadIdx.x;
    for (int e = tid; e < 16896; e += 256) {
        int h = e / 2112, r = e % 2112;
        float s = 0.0f;
        #pragma unroll
        for (int ch = 0; ch < 8; ++ch)
            s += kvpart[(size_t)((b * 8 + h) * 8 + ch) * 2112 + r];
        lds[e] = s;
    }
    __syncthreads();
    int l_loc = tid >> 2;
    int m0 = (tid & 3) * 8;
    int l = ltile * 64 + l_loc;
    float sn = snc[l * 2], cs = snc[l * 2 + 1];
    const float* qbase = &Qmat[(size_t)(b * LL + l) * CDIM];
    for (int h = 0; h < HEADS; ++h) {
        const float* kv = &lds[h * 2112];
        float q[32];
        #pragma unroll
        for (int j4 = 0; j4 < 8; ++j4) {
            float4 qv = *(const float4*)&qbase[h * 32 + j4 * 4];
            q[j4 * 4 + 0] = qv.x; q[j4 * 4 + 1] = qv.y;
            q[j4 * 4 + 2] = qv.z; q[j4 * 4 + 3] = qv.w;
        }
        float zs = 0.0f, zc = 0.0f;
        #pragma unroll
        for (int j = 0; j < 32; ++j) { zs += q[j] * kv[2048 + j]; zc += q[j] * kv[2080 + j]; }
        float den = sn * zs + cs * zc;
        float Z = 1.0f / fmaxf(den, 1e-6f);
        float outv[8];
        #pragma unroll
        for (int mi = 0; mi < 8; ++mi) {
            int mm = m0 + mi;
            float as = 0.0f, ac = 0.0f;
            #pragma unroll
            for (int j = 0; j < 32; ++j) {
                as += q[j] * kv[j * 32 + mm];
                ac += q[j] * kv[1024 + j * 32 + mm];
            }
            outv[mi] = (sn * as + cs * ac) * Z;
        }
        float* ob = &attnOut[(size_t)(b * LL + l) * CDIM + h * 32 + m0];
        *(float4*)&ob[0] = make_float4(outv[0], outv[1], outv[2], outv[3]);
        *(float4*)&ob[4] = make_float4(outv[4], outv[5], outv[6], outv[7]);
    }
}

// ---------------------------------------------------------------------------
// ffeat (b,L,256) -> (b,c,64,64) -> bilinear x2 (align_corners=False) * a3 -> out
__global__ __launch_bounds__(256) void resize_mul_kernel(
    const float* __restrict__ ffeat, const float* __restrict__ a3, float* __restrict__ out)
{
    __shared__ float ft[3][64][65];   // [src row k-1,k,k+1][cc][xs]
    int k = blockIdx.x, ct = blockIdx.y, b = blockIdx.z;
    int tid = threadIdx.x;
    for (int it = 0; it < 48; ++it) {
        int e = it * 256 + tid;
        int cc = e & 63;
        int xs = (e >> 6) & 63;
        int ys = e >> 12;
        int ysrc = min(max(k - 1 + ys, 0), 63);
        ft[ys][cc][xs] = ffeat[(size_t)(b * LL + ysrc * 64 + xs) * CDIM + ct * 64 + cc];
    }
    __syncthreads();
    int x = tid & 127;
    int half = tid >> 7;
    int y = 2 * k + half;
    int ysA, ysB; float wyA, wyB;
    if (half == 0) { ysA = 0; ysB = 1; wyA = 0.25f; wyB = 0.75f; }
    else           { ysA = 1; ysB = 2; wyA = 0.75f; wyB = 0.25f; }
    int x0; float wx1;
    if ((x & 1) == 0) { x0 = x / 2 - 1; wx1 = 0.75f; }
    else              { x0 = x / 2;     wx1 = 0.25f; }
    int x0c = max(x0, 0);
    int x1c = min(x0 + 1, 63);
    float wx0 = 1.0f - wx1;
    for (int cc = 0; cc < 64; ++cc) {
        float rA = wx0 * ft[ysA][cc][x0c] + wx1 * ft[ysA][cc][x1c];
        float rB = wx0 * ft[ysB][cc][x0c] + wx1 * ft[ysB][cc][x1c];
        float val = wyA * rA + wyB * rB;
        size_t oidx = ((size_t)(b * 256 + ct * 64 + cc) * 128 + y) * 128 + x;
        out[oidx] = val * a3[oidx];
    }
}

// ---------------------------------------------------------------------------
extern "C" void kernel_launch(void* const* d_in, const int* in_sizes, int n_in,
                              void* d_out, int out_size, void* d_ws, size_t ws_size,
                              hipStream_t stream)
{
    const float* a3     = (const float*)d_in[0];
    const float* a4     = (const float*)d_in[1];
    const float* q_w    = (const float*)d_in[2];
    const float* q_b    = (const float*)d_in[3];
    const float* q_ln_g = (const float*)d_in[4];
    const float* q_ln_b = (const float*)d_in[5];
    const float* k_w    = (const float*)d_in[6];
    const float* k_b    = (const float*)d_in[7];
    const float* k_ln_g = (const float*)d_in[8];
    const float* k_ln_b = (const float*)d_in[9];
    const float* v_w    = (const float*)d_in[10];
    const float* v_b    = (const float*)d_in[11];
    const float* out_w  = (const float*)d_in[12];
    const float* out_b  = (const float*)d_in[13];
    const float* lin1_w = (const float*)d_in[14];
    const float* lin1_b = (const float*)d_in[15];
    const float* lin2_w = (const float*)d_in[16];
    const float* lin2_b = (const float*)d_in[17];
    const float* n1_g   = (const float*)d_in[18];
    const float* n1_b   = (const float*)d_in[19];
    const float* n2_g   = (const float*)d_in[20];
    const float* n2_b   = (const float*)d_in[21];
    // d_in[22] = idx, always 2 for this input set (a3 pooled by 2, a4 untouched)
    float* out = (float*)d_out;
    float* ws = (float*)d_ws;

    const size_t o_pos = 0;
    const size_t o_snc = o_pos + (size_t)LL * CDIM;
    const size_t o_res = o_snc + 2 * LL;
    const size_t o_x3  = o_res + (size_t)NROWS * CDIM;
    const size_t o_x4  = o_x3  + (size_t)NROWS * CDIM;
    const size_t o_q   = o_x4  + (size_t)NROWS * CDIM;
    const size_t o_k   = o_q   + (size_t)NROWS * CDIM;
    const size_t o_v   = o_k   + (size_t)NROWS * CDIM;
    const size_t o_kvp = o_v   + (size_t)NROWS * CDIM;
    // reuse:
    const size_t o_attn  = o_x3;   // attnOut over x3
    const size_t o_res2  = o_x4;   // res2 over x4
    const size_t o_h1    = o_q;    // h1 (65536x1024) over Q,K,V,kvpart + extra
    const size_t o_ffeat = o_res;  // final features over residual

    pos_kernel<<<LL, 256, 0, stream>>>(ws + o_pos, ws + o_snc);
    pool_x3_kernel<<<dim3(64, 4, 16), 256, 0, stream>>>(a3, ws + o_res, ws + o_x3, ws + o_pos);
    x4_kernel<<<dim3(64, 4, 16), 256, 0, stream>>>(a4, ws + o_x4, ws + o_pos);

    // Q = relu(LN(x3 @ q_w + q_b)); K = relu(LN(x4 @ k_w + k_b)); V = x4 @ v_w + v_b
    gemm_fused<true, true, false, false><<<dim3(NROWS / 32, 1), 256, 0, stream>>>(
        ws + o_x3, q_w, q_b, q_ln_g, q_ln_b, nullptr, ws + o_q, 256, 256);
    gemm_fused<true, true, false, false><<<dim3(NROWS / 32, 1), 256, 0, stream>>>(
        ws + o_x4, k_w, k_b, k_ln_g, k_ln_b, nullptr, ws + o_k, 256, 256);
    gemm_fused<false, false, false, false><<<dim3(NROWS / 32, 1), 256, 0, stream>>>(
        ws + o_x4, v_w, v_b, nullptr, nullptr, nullptr, ws + o_v, 256, 256);

    kv_kernel<<<dim3(8, 128), 256, 0, stream>>>(ws + o_k, ws + o_v, ws + o_snc, ws + o_kvp);
    attn_kernel<<<dim3(64, 16), 256, 0, stream>>>(ws + o_q, ws + o_kvp, ws + o_snc, ws + o_attn);

    // out-proj + LN(n1) + residual -> res2
    gemm_fused<true, false, false, true><<<dim3(NROWS / 32, 1), 256, 0, stream>>>(
        ws + o_attn, out_w, out_b, n1_g, n1_b, ws + o_res, ws + o_res2, 256, 256);
    // MLP
    gemm_fused<false, false, true, false><<<dim3(NROWS / 32, 4), 256, 0, stream>>>(
        ws + o_res2, lin1_w, lin1_b, nullptr, nullptr, nullptr, ws + o_h1, 256, 1024);
    gemm_fused<true, false, false, true><<<dim3(NROWS / 32, 1), 256, 0, stream>>>(
        ws + o_h1, lin2_w, lin2_b, n2_g, n2_b, ws + o_res2, ws + o_ffeat, 1024, 256);

    resize_mul_kernel<<<dim3(64, 4, 16), 256, 0, stream>>>(ws + o_ffeat, a3, out);
}

// Round 2
// 754.771 us; speedup vs baseline: 2.4640x; 2.4640x over previous
//
#include <hip/hip_runtime.h>
#include <hip/hip_bf16.h>
#include <math.h>

#define HEADS 8
#define LL 4096
#define CDIM 256
#define BATCH 16
#define NROWS (BATCH*LL)

typedef __attribute__((ext_vector_type(8))) __bf16 bf16x8;
typedef __attribute__((ext_vector_type(4))) float f32x4;

__device__ inline float b2f(ushort u) {
    union { unsigned u; float f; } v; v.u = ((unsigned)u) << 16; return v.f;
}
__device__ inline ushort f2b(float f) {
    union { float f; unsigned u; } v; v.f = f;
    unsigned r = (v.u + 0x7FFF + ((v.u >> 16) & 1)) >> 16;
    return (ushort)r;
}
__device__ inline void gload16(const void* g, void* l) {
    __builtin_amdgcn_global_load_lds(
        (const __attribute__((address_space(1))) unsigned int*)g,
        (__attribute__((address_space(3))) unsigned int*)l, 16, 0, 0);
}

// ---------------------------------------------------------------------------
// pos table (4096 x 256) + cosFormer sin/cos table (4096 x 2)
__global__ void pos_kernel(float* __restrict__ pos, float* __restrict__ snc) {
    int l = blockIdx.x;
    int c = threadIdx.x;
    int y = l >> 6, x = l & 63;
    int k = c & 63;
    float omega = expf(-(float)k * (9.210340371976184f / 64.0f));  // ln(10000)/64
    float coord = (c < 128) ? (float)y : (float)x;
    float ang = coord * omega;
    float val = ((c & 127) < 64) ? sinf(ang) : cosf(ang);
    pos[l * CDIM + c] = val;
    if (c < 2) {
        float wi = 1.5707963267948966f * (float)(l + 1) / (float)LL;
        snc[l * 2 + c] = (c == 0) ? sinf(wi) : cosf(wi);
    }
}

// ---------------------------------------------------------------------------
// weight transpose + bf16 convert: W[K][N] f32 -> Wt[N][K] bf16
__global__ __launch_bounds__(256) void wt_kernel(
    const float* __restrict__ W, ushort* __restrict__ Wt, int K, int N)
{
    __shared__ float t[32][33];
    int kb = blockIdx.x * 32, nb = blockIdx.y * 32;
    int x = threadIdx.x & 31, y = threadIdx.x >> 5;   // y: 0..7
    #pragma unroll
    for (int i = 0; i < 4; ++i)
        t[y + i * 8][x] = W[(size_t)(kb + y + i * 8) * N + nb + x];
    __syncthreads();
    #pragma unroll
    for (int i = 0; i < 4; ++i) {
        int n = y + i * 8;
        Wt[(size_t)(nb + n) * K + kb + x] = f2b(t[x][n]);
    }
}

// ---------------------------------------------------------------------------
// a3 (b,256,128,128) --avgpool2--> residual f32 (b,L,256), x3 bf16 = residual + pos
__global__ __launch_bounds__(256) void pool_x3_kernel(
    const float* __restrict__ a3, float* __restrict__ residual,
    ushort* __restrict__ x3b, const float* __restrict__ pos)
{
    __shared__ float raw[64][128];
    __shared__ float pooled[64][65];
    int i = blockIdx.x, ct = blockIdx.y, b = blockIdx.z;
    int tid = threadIdx.x;
    #pragma unroll
    for (int it = 0; it < 8; ++it) {
        int lin = (it * 256 + tid) * 4;
        int x = lin & 127;
        int cc = lin >> 7;
        size_t base = ((size_t)(b * 256 + ct * 64 + cc) * 128 + 2 * i) * 128 + x;
        float4 v0 = *(const float4*)&a3[base];
        float4 v1 = *(const float4*)&a3[base + 128];
        float4 s = make_float4(v0.x + v1.x, v0.y + v1.y, v0.z + v1.z, v0.w + v1.w);
        *(float4*)&raw[cc][x] = s;
    }
    __syncthreads();
    #pragma unroll
    for (int it = 0; it < 16; ++it) {
        int idx = it * 256 + tid;
        int j = idx & 63, cc = idx >> 6;
        pooled[cc][j] = 0.25f * (raw[cc][2 * j] + raw[cc][2 * j + 1]);
    }
    __syncthreads();
    #pragma unroll
    for (int it = 0; it < 16; ++it) {
        int cc = tid & 63;
        int jj = (tid >> 6) + it * 4;
        float val = pooled[cc][jj];
        int l = i * 64 + jj;
        int c = ct * 64 + cc;
        size_t o = (size_t)(b * LL + l) * CDIM + c;
        residual[o] = val;
        x3b[o] = f2b(val + pos[l * CDIM + c]);
    }
}

// ---------------------------------------------------------------------------
// a4 (b,256,64,64) --transpose--> x4 bf16 (b,L,256) + pos
__global__ __launch_bounds__(256) void x4_kernel(
    const float* __restrict__ a4, ushort* __restrict__ x4b, const float* __restrict__ pos)
{
    __shared__ float t2[64][65];
    int y = blockIdx.x, ct = blockIdx.y, b = blockIdx.z, tid = threadIdx.x;
    #pragma unroll
    for (int it = 0; it < 16; ++it) {
        int idx = it * 256 + tid;
        int x = idx & 63, cc = idx >> 6;
        t2[cc][x] = a4[((size_t)(b * 256 + ct * 64 + cc) * 64 + y) * 64 + x];
    }
    __syncthreads();
    #pragma unroll
    for (int it = 0; it < 16; ++it) {
        int cc = tid & 63;
        int xx = (tid >> 6) + it * 4;
        int l = y * 64 + xx, c = ct * 64 + cc;
        x4b[(size_t)(b * LL + l) * CDIM + c] = f2b(t2[cc][xx] + pos[l * CDIM + c]);
    }
}

// ---------------------------------------------------------------------------
// MFMA GEMM: out = epilogue(A @ Wt^T + bias); A: N x K bf16, Wt: colsTot x K bf16.
// Block: 64 rows x 256 cols, 4 waves; wave w -> cols w*64..w*64+63, 4x4 frags 16x16.
// LDS staged via global_load_lds, XOR-swizzled source (slot = g ^ ((row>>1)&3)).
template<bool DO_LN, bool DO_RELU, bool DO_GELU, bool DO_RES, bool W_BF, bool W_F32>
__global__ __launch_bounds__(256, 2) void gemm_mfma(
    const ushort* __restrict__ A, const ushort* __restrict__ Wt,
    const float* __restrict__ bias, const float* __restrict__ gam_,
    const float* __restrict__ bet_, const float* __restrict__ res,
    ushort* __restrict__ outb, float* __restrict__ outf,
    int K, int colsTot)
{
    __shared__ ushort As[64 * 32];     // [row][32k], 64B rows, swizzled 16B slots
    __shared__ ushort Bs[256 * 32];    // [col][32k]
    __shared__ float redS[64][4];
    __shared__ float redQ[64][4];
    __shared__ float2 mustd[64];

    const int tid = threadIdx.x;
    const int lane = tid & 63;
    const int wv = tid >> 6;
    const int wvu = __builtin_amdgcn_readfirstlane(wv);
    const int row0 = blockIdx.x * 64;
    const int cb = blockIdx.y * 256;

    // staging source (pre-swizzled k-group)
    const int sr = tid >> 2;                      // row/col index 0..63
    const int sg = (tid & 3) ^ ((sr >> 1) & 3);   // source k-group for linear slot
    const ushort* aSrc = A + (size_t)(row0 + sr) * K + sg * 8;
    const ushort* bSrc = Wt + (size_t)(cb + sr) * K + sg * 8;   // + j*64*K per j

    // fragment-read swizzle slot (same for A and B since f*16, wv*64 are 0 mod 4 after >>1&3)
    const int frSlot = (lane >> 4) ^ (((lane & 15) >> 1) & 3);

    f32x4 acc[4][4] = {};
    for (int kb = 0; kb < K; kb += 32) {
        gload16(aSrc + kb, (char*)&As[0] + wvu * 1024);
        #pragma unroll
        for (int j = 0; j < 4; ++j)
            gload16(bSrc + (size_t)j * 64 * K + kb, (char*)&Bs[0] + j * 4096 + wvu * 1024);
        __syncthreads();

        bf16x8 af[4], bfr[4];
        #pragma unroll
        for (int f = 0; f < 4; ++f) {
            int r = f * 16 + (lane & 15);
            af[f] = *(const bf16x8*)&As[r * 32 + frSlot * 8];
            int c = wv * 64 + f * 16 + (lane & 15);
            bfr[f] = *(const bf16x8*)&Bs[c * 32 + frSlot * 8];
        }
        #pragma unroll
        for (int fi = 0; fi < 4; ++fi)
            #pragma unroll
            for (int fj = 0; fj < 4; ++fj)
                acc[fi][fj] = __builtin_amdgcn_mfma_f32_16x16x32_bf16(
                    af[fi], bfr[fj], acc[fi][fj], 0, 0, 0);
        __syncthreads();
    }

    const int cl = lane & 15;
    const int rg = lane >> 4;
    float bia[4], gmv[4], btv[4];
    #pragma unroll
    for (int fj = 0; fj < 4; ++fj) {
        int col = cb + wv * 64 + fj * 16 + cl;
        bia[fj] = bias[col];
        if constexpr (DO_LN) { gmv[fj] = gam_[col]; btv[fj] = bet_[col]; }
    }
    #pragma unroll
    for (int fi = 0; fi < 4; ++fi)
        #pragma unroll
        for (int fj = 0; fj < 4; ++fj)
            #pragma unroll
            for (int j = 0; j < 4; ++j)
                acc[fi][fj][j] += bia[fj];

    if constexpr (DO_LN) {   // requires colsTot == 256, gridDim.y == 1
        #pragma unroll
        for (int fi = 0; fi < 4; ++fi)
            #pragma unroll
            for (int j = 0; j < 4; ++j) {
                float s = acc[fi][0][j] + acc[fi][1][j] + acc[fi][2][j] + acc[fi][3][j];
                float q = acc[fi][0][j] * acc[fi][0][j] + acc[fi][1][j] * acc[fi][1][j]
                        + acc[fi][2][j] * acc[fi][2][j] + acc[fi][3][j] * acc[fi][3][j];
                #pragma unroll
                for (int m = 1; m <= 8; m <<= 1) {
                    s += __shfl_xor(s, m, 64);
                    q += __shfl_xor(q, m, 64);
                }
                if (cl == 0) { redS[fi * 16 + rg * 4 + j][wv] = s; redQ[fi * 16 + rg * 4 + j][wv] = q; }
            }
        __syncthreads();
        if (tid < 64) {
            float s = redS[tid][0] + redS[tid][1] + redS[tid][2] + redS[tid][3];
            float q = redQ[tid][0] + redQ[tid][1] + redQ[tid][2] + redQ[tid][3];
            float mu = s * (1.0f / 256.0f);
            float var = q * (1.0f / 256.0f) - mu * mu;
            mustd[tid] = make_float2(mu, rsqrtf(var + 1e-5f));
        }
        __syncthreads();
        #pragma unroll
        for (int fi = 0; fi < 4; ++fi)
            #pragma unroll
            for (int j = 0; j < 4; ++j) {
                float2 ms = mustd[fi * 16 + rg * 4 + j];
                #pragma unroll
                for (int fj = 0; fj < 4; ++fj)
                    acc[fi][fj][j] = (acc[fi][fj][j] - ms.x) * ms.y * gmv[fj] + btv[fj];
            }
    }
    if constexpr (DO_RELU) {
        #pragma unroll
        for (int fi = 0; fi < 4; ++fi)
            #pragma unroll
            for (int fj = 0; fj < 4; ++fj)
                #pragma unroll
                for (int j = 0; j < 4; ++j)
                    acc[fi][fj][j] = fmaxf(acc[fi][fj][j], 0.0f);
    }
    if constexpr (DO_GELU) {
        #pragma unroll
        for (int fi = 0; fi < 4; ++fi)
            #pragma unroll
            for (int fj = 0; fj < 4; ++fj)
                #pragma unroll
                for (int j = 0; j < 4; ++j) {
                    float v = acc[fi][fj][j];
                    acc[fi][fj][j] = 0.5f * v * (1.0f + erff(v * 0.7071067811865476f));
                }
    }
    #pragma unroll
    for (int fi = 0; fi < 4; ++fi)
        #pragma unroll
        for (int j = 0; j < 4; ++j) {
            size_t row = row0 + fi * 16 + rg * 4 + j;
            size_t rbase = row * (size_t)colsTot + cb + wv * 64 + cl;
            #pragma unroll
            for (int fj = 0; fj < 4; ++fj) {
                float v = acc[fi][fj][j];
                if constexpr (DO_RES) v += res[rbase + fj * 16];
                if constexpr (W_F32) outf[rbase + fj * 16] = v;
                if constexpr (W_BF) outb[rbase + fj * 16] = f2b(v);
            }
        }
}

// ---------------------------------------------------------------------------
// cosFormer stage 1 (bf16 in): partial KVs/KVc (32x32) + weighted Ksums per (b,h,chunk)
__global__ __launch_bounds__(256) void kv_kernel(
    const ushort* __restrict__ Kmat, const ushort* __restrict__ Vmat,
    const float* __restrict__ snc, float* __restrict__ kvpart)
{
    __shared__ float Kt[64][32];
    __shared__ float Vt[64][32];
    __shared__ float sns[64], css[64];
    int chunk = blockIdx.x;
    int bh = blockIdx.y;
    int b = bh >> 3, h = bh & 7;
    int tid = threadIdx.x;
    int m = tid & 31;
    int d0 = (tid >> 5) * 4;
    float accs[4] = {}, accc[4] = {};
    float kss[4] = {}, ksc[4] = {};
    int l0chunk = chunk * 512;
    for (int sub = 0; sub < 8; ++sub) {
        int l0 = l0chunk + sub * 64;
        int ltb = tid >> 5;
        int col = tid & 31;
        #pragma unroll
        for (int it = 0; it < 8; ++it) {
            int ll = ltb + it * 8;
            size_t base = (size_t)(b * LL + l0 + ll) * CDIM + h * 32 + col;
            Kt[ll][col] = b2f(Kmat[base]);
            Vt[ll][col] = b2f(Vmat[base]);
        }
        if (tid < 64) { sns[tid] = snc[(l0 + tid) * 2]; css[tid] = snc[(l0 + tid) * 2 + 1]; }
        __syncthreads();
        for (int lt = 0; lt < 64; ++lt) {
            float s = sns[lt], c = css[lt];
            float v = Vt[lt][m];
            #pragma unroll
            for (int i2 = 0; i2 < 4; ++i2) {
                float kd = Kt[lt][d0 + i2];
                float t1 = kd * v;
                accs[i2] += t1 * s;
                accc[i2] += t1 * c;
                kss[i2] += kd * s;
                ksc[i2] += kd * c;
            }
        }
        __syncthreads();
    }
    size_t base = (size_t)(bh * 8 + chunk) * 2112;
    #pragma unroll
    for (int i2 = 0; i2 < 4; ++i2) {
        kvpart[base + (d0 + i2) * 32 + m] = accs[i2];
        kvpart[base + 1024 + (d0 + i2) * 32 + m] = accc[i2];
        if (m == 0) {
            kvpart[base + 2048 + d0 + i2] = kss[i2];
            kvpart[base + 2080 + d0 + i2] = ksc[i2];
        }
    }
}

// ---------------------------------------------------------------------------
// cosFormer stage 2 (bf16 Q in, bf16 attn out)
__global__ __launch_bounds__(256) void attn_kernel(
    const ushort* __restrict__ Qmat, const float* __restrict__ kvpart,
    const float* __restrict__ snc, ushort* __restrict__ attnOut)
{
    __shared__ float lds[16896];   // 8 heads x 2112
    int ltile = blockIdx.x;
    int b = blockIdx.y;
    int tid = threadIdx.x;
    for (int e = tid; e < 16896; e += 256) {
        int h = e / 2112, r = e % 2112;
        float s = 0.0f;
        #pragma unroll
        for (int ch = 0; ch < 8; ++ch)
            s += kvpart[(size_t)((b * 8 + h) * 8 + ch) * 2112 + r];
        lds[e] = s;
    }
    __syncthreads();
    int l_loc = tid >> 2;
    int m0 = (tid & 3) * 8;
    int l = ltile * 64 + l_loc;
    float sn = snc[l * 2], cs = snc[l * 2 + 1];
    const ushort* qbase = &Qmat[(size_t)(b * LL + l) * CDIM];
    for (int h = 0; h < HEADS; ++h) {
        const float* kv = &lds[h * 2112];
        float q[32];
        #pragma unroll
        for (int j8 = 0; j8 < 4; ++j8) {
            uint4 raw = *(const uint4*)&qbase[h * 32 + j8 * 8];
            q[j8 * 8 + 0] = b2f((ushort)(raw.x & 0xffff)); q[j8 * 8 + 1] = b2f((ushort)(raw.x >> 16));
            q[j8 * 8 + 2] = b2f((ushort)(raw.y & 0xffff)); q[j8 * 8 + 3] = b2f((ushort)(raw.y >> 16));
            q[j8 * 8 + 4] = b2f((ushort)(raw.z & 0xffff)); q[j8 * 8 + 5] = b2f((ushort)(raw.z >> 16));
            q[j8 * 8 + 6] = b2f((ushort)(raw.w & 0xffff)); q[j8 * 8 + 7] = b2f((ushort)(raw.w >> 16));
        }
        float zs = 0.0f, zc = 0.0f;
        #pragma unroll
        for (int j = 0; j < 32; ++j) { zs += q[j] * kv[2048 + j]; zc += q[j] * kv[2080 + j]; }
        float den = sn * zs + cs * zc;
        float Z = 1.0f / fmaxf(den, 1e-6f);
        float outv[8];
        #pragma unroll
        for (int mi = 0; mi < 8; ++mi) {
            int mm = m0 + mi;
            float as = 0.0f, ac = 0.0f;
            #pragma unroll
            for (int j = 0; j < 32; ++j) {
                as += q[j] * kv[j * 32 + mm];
                ac += q[j] * kv[1024 + j * 32 + mm];
            }
            outv[mi] = (sn * as + cs * ac) * Z;
        }
        uint4 ov;
        ov.x = f2b(outv[0]) | ((unsigned)f2b(outv[1]) << 16);
        ov.y = f2b(outv[2]) | ((unsigned)f2b(outv[3]) << 16);
        ov.z = f2b(outv[4]) | ((unsigned)f2b(outv[5]) << 16);
        ov.w = f2b(outv[6]) | ((unsigned)f2b(outv[7]) << 16);
        *(uint4*)&attnOut[(size_t)(b * LL + l) * CDIM + h * 32 + m0] = ov;
    }
}

// ---------------------------------------------------------------------------
// ffeat f32 (b,L,256) -> (b,c,64,64) -> bilinear x2 * a3 -> out
__global__ __launch_bounds__(256) void resize_mul_kernel(
    const float* __restrict__ ffeat, const float* __restrict__ a3, float* __restrict__ out)
{
    __shared__ float ft[3][64][65];
    int k = blockIdx.x, ct = blockIdx.y, b = blockIdx.z;
    int tid = threadIdx.x;
    for (int it = 0; it < 48; ++it) {
        int e = it * 256 + tid;
        int cc = e & 63;
        int xs = (e >> 6) & 63;
        int ys = e >> 12;
        int ysrc = min(max(k - 1 + ys, 0), 63);
        ft[ys][cc][xs] = ffeat[(size_t)(b * LL + ysrc * 64 + xs) * CDIM + ct * 64 + cc];
    }
    __syncthreads();
    int x = tid & 127;
    int half = tid >> 7;
    int y = 2 * k + half;
    int ysA, ysB; float wyA, wyB;
    if (half == 0) { ysA = 0; ysB = 1; wyA = 0.25f; wyB = 0.75f; }
    else           { ysA = 1; ysB = 2; wyA = 0.75f; wyB = 0.25f; }
    int x0; float wx1;
    if ((x & 1) == 0) { x0 = x / 2 - 1; wx1 = 0.75f; }
    else              { x0 = x / 2;     wx1 = 0.25f; }
    int x0c = max(x0, 0);
    int x1c = min(x0 + 1, 63);
    float wx0 = 1.0f - wx1;
    for (int cc = 0; cc < 64; ++cc) {
        float rA = wx0 * ft[ysA][cc][x0c] + wx1 * ft[ysA][cc][x1c];
        float rB = wx0 * ft[ysB][cc][x0c] + wx1 * ft[ysB][cc][x1c];
        float val = wyA * rA + wyB * rB;
        size_t oidx = ((size_t)(b * 256 + ct * 64 + cc) * 128 + y) * 128 + x;
        out[oidx] = val * a3[oidx];
    }
}

// ---------------------------------------------------------------------------
extern "C" void kernel_launch(void* const* d_in, const int* in_sizes, int n_in,
                              void* d_out, int out_size, void* d_ws, size_t ws_size,
                              hipStream_t stream)
{
    const float* a3     = (const float*)d_in[0];
    const float* a4     = (const float*)d_in[1];
    const float* q_w    = (const float*)d_in[2];
    const float* q_b    = (const float*)d_in[3];
    const float* q_ln_g = (const float*)d_in[4];
    const float* q_ln_b = (const float*)d_in[5];
    const float* k_w    = (const float*)d_in[6];
    const float* k_b    = (const float*)d_in[7];
    const float* k_ln_g = (const float*)d_in[8];
    const float* k_ln_b = (const float*)d_in[9];
    const float* v_w    = (const float*)d_in[10];
    const float* v_b    = (const float*)d_in[11];
    const float* out_w  = (const float*)d_in[12];
    const float* out_b  = (const float*)d_in[13];
    const float* lin1_w = (const float*)d_in[14];
    const float* lin1_b = (const float*)d_in[15];
    const float* lin2_w = (const float*)d_in[16];
    const float* lin2_b = (const float*)d_in[17];
    const float* n1_g   = (const float*)d_in[18];
    const float* n1_b   = (const float*)d_in[19];
    const float* n2_g   = (const float*)d_in[20];
    const float* n2_b   = (const float*)d_in[21];
    float* out = (float*)d_out;
    char* base = (char*)d_ws;

    const size_t MiB = 1024 * 1024;
    float*  pos      = (float*)(base);                       // 4 MiB
    float*  snc      = (float*)(base + 4 * MiB);             // 32 KiB
    ushort* wqT      = (ushort*)(base + 4 * MiB + 64 * 1024);
    ushort* wkT      = wqT + 256 * 256;
    ushort* wvT      = wkT + 256 * 256;
    ushort* woT      = wvT + 256 * 256;
    ushort* w1T      = woT + 256 * 256;       // [1024][256]
    ushort* w2T      = w1T + 1024 * 256;      // [256][1024]
    float*  residual = (float*)(base + 6 * MiB);             // 64 MiB (ffeat reuses)
    ushort* x3b      = (ushort*)(base + 70 * MiB);           // 32 MiB (attnb reuses)
    ushort* x4b      = (ushort*)(base + 102 * MiB);          // 32 MiB (res2b reuses)
    ushort* Qb       = (ushort*)(base + 134 * MiB);
    ushort* Kb       = (ushort*)(base + 166 * MiB);
    ushort* Vb       = (ushort*)(base + 198 * MiB);
    float*  kvp      = (float*)(base + 230 * MiB);           // 8.3 MiB
    float*  res2f    = (float*)(base + 239 * MiB);           // 64 MiB
    ushort* h1b      = (ushort*)(base + 303 * MiB);          // 128 MiB -> 431 MiB total
    ushort* attnb    = x3b;
    ushort* res2b    = x4b;
    float*  ffeat    = residual;

    pos_kernel<<<LL, 256, 0, stream>>>(pos, snc);
    wt_kernel<<<dim3(8, 8), 256, 0, stream>>>(q_w, wqT, 256, 256);
    wt_kernel<<<dim3(8, 8), 256, 0, stream>>>(k_w, wkT, 256, 256);
    wt_kernel<<<dim3(8, 8), 256, 0, stream>>>(v_w, wvT, 256, 256);
    wt_kernel<<<dim3(8, 8), 256, 0, stream>>>(out_w, woT, 256, 256);
    wt_kernel<<<dim3(8, 32), 256, 0, stream>>>(lin1_w, w1T, 256, 1024);
    wt_kernel<<<dim3(32, 8), 256, 0, stream>>>(lin2_w, w2T, 1024, 256);

    pool_x3_kernel<<<dim3(64, 4, 16), 256, 0, stream>>>(a3, residual, x3b, pos);
    x4_kernel<<<dim3(64, 4, 16), 256, 0, stream>>>(a4, x4b, pos);

    // Q = relu(LN(x3@q_w+b)); K = relu(LN(x4@k_w+b)); V = x4@v_w+b
    gemm_mfma<true, true, false, false, true, false><<<dim3(NROWS / 64, 1), 256, 0, stream>>>(
        x3b, wqT, q_b, q_ln_g, q_ln_b, nullptr, Qb, nullptr, 256, 256);
    gemm_mfma<true, true, false, false, true, false><<<dim3(NROWS / 64, 1), 256, 0, stream>>>(
        x4b, wkT, k_b, k_ln_g, k_ln_b, nullptr, Kb, nullptr, 256, 256);
    gemm_mfma<false, false, false, false, true, false><<<dim3(NROWS / 64, 1), 256, 0, stream>>>(
        x4b, wvT, v_b, nullptr, nullptr, nullptr, Vb, nullptr, 256, 256);

    kv_kernel<<<dim3(8, 128), 256, 0, stream>>>(Kb, Vb, snc, kvp);
    attn_kernel<<<dim3(64, 16), 256, 0, stream>>>(Qb, kvp, snc, attnb);

    // out-proj + LN(n1) + residual -> res2 (bf16 + f32)
    gemm_mfma<true, false, false, true, true, true><<<dim3(NROWS / 64, 1), 256, 0, stream>>>(
        attnb, woT, out_b, n1_g, n1_b, residual, res2b, res2f, 256, 256);
    // MLP
    gemm_mfma<false, false, true, false, true, false><<<dim3(NROWS / 64, 4), 256, 0, stream>>>(
        res2b, w1T, lin1_b, nullptr, nullptr, nullptr, h1b, nullptr, 256, 1024);
    gemm_mfma<true, false, false, true, false, true><<<dim3(NROWS / 64, 1), 256, 0, stream>>>(
        h1b, w2T, lin2_b, n2_g, n2_b, res2f, nullptr, ffeat, 1024, 256);

    resize_mul_kernel<<<dim3(64, 4, 16), 256, 0, stream>>>(ffeat, a3, out);
}

// Round 3
// 654.557 us; speedup vs baseline: 2.8413x; 1.1531x over previous
//
#include <hip/hip_runtime.h>
#include <hip/hip_bf16.h>
#include <math.h>

#define HEADS 8
#define LL 4096
#define CDIM 256
#define BATCH 16
#define NROWS (BATCH*LL)

typedef __attribute__((ext_vector_type(8))) __bf16 bf16x8;
typedef __attribute__((ext_vector_type(4))) float f32x4;

__device__ inline float b2f(ushort u) {
    union { unsigned u; float f; } v; v.u = ((unsigned)u) << 16; return v.f;
}
__device__ inline ushort f2b(float f) {
    union { float f; unsigned u; } v; v.f = f;
    unsigned r = (v.u + 0x7FFF + ((v.u >> 16) & 1)) >> 16;
    return (ushort)r;
}
__device__ inline void gload16(const void* g, void* l) {
    __builtin_amdgcn_global_load_lds(
        (const __attribute__((address_space(1))) unsigned int*)g,
        (__attribute__((address_space(3))) unsigned int*)l, 16, 0, 0);
}

// ---------------------------------------------------------------------------
// pos table (4096 x 256) + cosFormer sin/cos table (4096 x 2)
__global__ void pos_kernel(float* __restrict__ pos, float* __restrict__ snc) {
    int l = blockIdx.x;
    int c = threadIdx.x;
    int y = l >> 6, x = l & 63;
    int k = c & 63;
    float omega = expf(-(float)k * (9.210340371976184f / 64.0f));  // ln(10000)/64
    float coord = (c < 128) ? (float)y : (float)x;
    float ang = coord * omega;
    float val = ((c & 127) < 64) ? sinf(ang) : cosf(ang);
    pos[l * CDIM + c] = val;
    if (c < 2) {
        float wi = 1.5707963267948966f * (float)(l + 1) / (float)LL;
        snc[l * 2 + c] = (c == 0) ? sinf(wi) : cosf(wi);
    }
}

// ---------------------------------------------------------------------------
// weight transpose + bf16 convert: W[K][N] f32 -> Wt[N][K] bf16
__global__ __launch_bounds__(256) void wt_kernel(
    const float* __restrict__ W, ushort* __restrict__ Wt, int K, int N)
{
    __shared__ float t[32][33];
    int kb = blockIdx.x * 32, nb = blockIdx.y * 32;
    int x = threadIdx.x & 31, y = threadIdx.x >> 5;   // y: 0..7
    #pragma unroll
    for (int i = 0; i < 4; ++i)
        t[y + i * 8][x] = W[(size_t)(kb + y + i * 8) * N + nb + x];
    __syncthreads();
    #pragma unroll
    for (int i = 0; i < 4; ++i) {
        int n = y + i * 8;
        Wt[(size_t)(nb + n) * K + kb + x] = f2b(t[x][n]);
    }
}

// ---------------------------------------------------------------------------
// a3 (b,256,128,128) --avgpool2--> residual f32 (b,L,256), x3 bf16 = residual + pos
__global__ __launch_bounds__(256) void pool_x3_kernel(
    const float* __restrict__ a3, float* __restrict__ residual,
    ushort* __restrict__ x3b, const float* __restrict__ pos)
{
    __shared__ float raw[64][128];
    __shared__ float pooled[64][65];
    int i = blockIdx.x, ct = blockIdx.y, b = blockIdx.z;
    int tid = threadIdx.x;
    #pragma unroll
    for (int it = 0; it < 8; ++it) {
        int lin = (it * 256 + tid) * 4;
        int x = lin & 127;
        int cc = lin >> 7;
        size_t base = ((size_t)(b * 256 + ct * 64 + cc) * 128 + 2 * i) * 128 + x;
        float4 v0 = *(const float4*)&a3[base];
        float4 v1 = *(const float4*)&a3[base + 128];
        float4 s = make_float4(v0.x + v1.x, v0.y + v1.y, v0.z + v1.z, v0.w + v1.w);
        *(float4*)&raw[cc][x] = s;
    }
    __syncthreads();
    #pragma unroll
    for (int it = 0; it < 16; ++it) {
        int idx = it * 256 + tid;
        int j = idx & 63, cc = idx >> 6;
        pooled[cc][j] = 0.25f * (raw[cc][2 * j] + raw[cc][2 * j + 1]);
    }
    __syncthreads();
    #pragma unroll
    for (int it = 0; it < 16; ++it) {
        int cc = tid & 63;
        int jj = (tid >> 6) + it * 4;
        float val = pooled[cc][jj];
        int l = i * 64 + jj;
        int c = ct * 64 + cc;
        size_t o = (size_t)(b * LL + l) * CDIM + c;
        residual[o] = val;
        x3b[o] = f2b(val + pos[l * CDIM + c]);
    }
}

// ---------------------------------------------------------------------------
// a4 (b,256,64,64) --transpose--> x4 bf16 (b,L,256) + pos
__global__ __launch_bounds__(256) void x4_kernel(
    const float* __restrict__ a4, ushort* __restrict__ x4b, const float* __restrict__ pos)
{
    __shared__ float t2[64][65];
    int y = blockIdx.x, ct = blockIdx.y, b = blockIdx.z, tid = threadIdx.x;
    #pragma unroll
    for (int it = 0; it < 16; ++it) {
        int idx = it * 256 + tid;
        int x = idx & 63, cc = idx >> 6;
        t2[cc][x] = a4[((size_t)(b * 256 + ct * 64 + cc) * 64 + y) * 64 + x];
    }
    __syncthreads();
    #pragma unroll
    for (int it = 0; it < 16; ++it) {
        int cc = tid & 63;
        int xx = (tid >> 6) + it * 4;
        int l = y * 64 + xx, c = ct * 64 + cc;
        x4b[(size_t)(b * LL + l) * CDIM + c] = f2b(t2[cc][xx] + pos[l * CDIM + c]);
    }
}

// ---------------------------------------------------------------------------
// MFMA GEMM: out = epilogue(A @ Wt^T + bias); A: N x K bf16, Wt: colsTot x K bf16.
template<bool DO_LN, bool DO_RELU, bool DO_GELU, bool DO_RES, bool W_BF, bool W_F32>
__global__ __launch_bounds__(256, 2) void gemm_mfma(
    const ushort* __restrict__ A, const ushort* __restrict__ Wt,
    const float* __restrict__ bias, const float* __restrict__ gam_,
    const float* __restrict__ bet_, const float* __restrict__ res,
    ushort* __restrict__ outb, float* __restrict__ outf,
    int K, int colsTot)
{
    __shared__ ushort As[64 * 32];     // [row][32k], 64B rows, swizzled 16B slots
    __shared__ ushort Bs[256 * 32];    // [col][32k]
    __shared__ float redS[64][4];
    __shared__ float redQ[64][4];
    __shared__ float2 mustd[64];

    const int tid = threadIdx.x;
    const int lane = tid & 63;
    const int wv = tid >> 6;
    const int wvu = __builtin_amdgcn_readfirstlane(wv);
    const int row0 = blockIdx.x * 64;
    const int cb = blockIdx.y * 256;

    const int sr = tid >> 2;
    const int sg = (tid & 3) ^ ((sr >> 1) & 3);
    const ushort* aSrc = A + (size_t)(row0 + sr) * K + sg * 8;
    const ushort* bSrc = Wt + (size_t)(cb + sr) * K + sg * 8;

    const int frSlot = (lane >> 4) ^ (((lane & 15) >> 1) & 3);

    f32x4 acc[4][4] = {};
    for (int kb = 0; kb < K; kb += 32) {
        gload16(aSrc + kb, (char*)&As[0] + wvu * 1024);
        #pragma unroll
        for (int j = 0; j < 4; ++j)
            gload16(bSrc + (size_t)j * 64 * K + kb, (char*)&Bs[0] + j * 4096 + wvu * 1024);
        __syncthreads();

        bf16x8 af[4], bfr[4];
        #pragma unroll
        for (int f = 0; f < 4; ++f) {
            int r = f * 16 + (lane & 15);
            af[f] = *(const bf16x8*)&As[r * 32 + frSlot * 8];
            int c = wv * 64 + f * 16 + (lane & 15);
            bfr[f] = *(const bf16x8*)&Bs[c * 32 + frSlot * 8];
        }
        #pragma unroll
        for (int fi = 0; fi < 4; ++fi)
            #pragma unroll
            for (int fj = 0; fj < 4; ++fj)
                acc[fi][fj] = __builtin_amdgcn_mfma_f32_16x16x32_bf16(
                    af[fi], bfr[fj], acc[fi][fj], 0, 0, 0);
        __syncthreads();
    }

    const int cl = lane & 15;
    const int rg = lane >> 4;
    float bia[4], gmv[4], btv[4];
    #pragma unroll
    for (int fj = 0; fj < 4; ++fj) {
        int col = cb + wv * 64 + fj * 16 + cl;
        bia[fj] = bias[col];
        if constexpr (DO_LN) { gmv[fj] = gam_[col]; btv[fj] = bet_[col]; }
    }
    #pragma unroll
    for (int fi = 0; fi < 4; ++fi)
        #pragma unroll
        for (int fj = 0; fj < 4; ++fj)
            #pragma unroll
            for (int j = 0; j < 4; ++j)
                acc[fi][fj][j] += bia[fj];

    if constexpr (DO_LN) {
        #pragma unroll
        for (int fi = 0; fi < 4; ++fi)
            #pragma unroll
            for (int j = 0; j < 4; ++j) {
                float s = acc[fi][0][j] + acc[fi][1][j] + acc[fi][2][j] + acc[fi][3][j];
                float q = acc[fi][0][j] * acc[fi][0][j] + acc[fi][1][j] * acc[fi][1][j]
                        + acc[fi][2][j] * acc[fi][2][j] + acc[fi][3][j] * acc[fi][3][j];
                #pragma unroll
                for (int m = 1; m <= 8; m <<= 1) {
                    s += __shfl_xor(s, m, 64);
                    q += __shfl_xor(q, m, 64);
                }
                if (cl == 0) { redS[fi * 16 + rg * 4 + j][wv] = s; redQ[fi * 16 + rg * 4 + j][wv] = q; }
            }
        __syncthreads();
        if (tid < 64) {
            float s = redS[tid][0] + redS[tid][1] + redS[tid][2] + redS[tid][3];
            float q = redQ[tid][0] + redQ[tid][1] + redQ[tid][2] + redQ[tid][3];
            float mu = s * (1.0f / 256.0f);
            float var = q * (1.0f / 256.0f) - mu * mu;
            mustd[tid] = make_float2(mu, rsqrtf(var + 1e-5f));
        }
        __syncthreads();
        #pragma unroll
        for (int fi = 0; fi < 4; ++fi)
            #pragma unroll
            for (int j = 0; j < 4; ++j) {
                float2 ms = mustd[fi * 16 + rg * 4 + j];
                #pragma unroll
                for (int fj = 0; fj < 4; ++fj)
                    acc[fi][fj][j] = (acc[fi][fj][j] - ms.x) * ms.y * gmv[fj] + btv[fj];
            }
    }
    if constexpr (DO_RELU) {
        #pragma unroll
        for (int fi = 0; fi < 4; ++fi)
            #pragma unroll
            for (int fj = 0; fj < 4; ++fj)
                #pragma unroll
                for (int j = 0; j < 4; ++j)
                    acc[fi][fj][j] = fmaxf(acc[fi][fj][j], 0.0f);
    }
    if constexpr (DO_GELU) {
        #pragma unroll
        for (int fi = 0; fi < 4; ++fi)
            #pragma unroll
            for (int fj = 0; fj < 4; ++fj)
                #pragma unroll
                for (int j = 0; j < 4; ++j) {
                    float v = acc[fi][fj][j];
                    acc[fi][fj][j] = 0.5f * v * (1.0f + erff(v * 0.7071067811865476f));
                }
    }
    #pragma unroll
    for (int fi = 0; fi < 4; ++fi)
        #pragma unroll
        for (int j = 0; j < 4; ++j) {
            size_t row = row0 + fi * 16 + rg * 4 + j;
            size_t rbase = row * (size_t)colsTot + cb + wv * 64 + cl;
            #pragma unroll
            for (int fj = 0; fj < 4; ++fj) {
                float v = acc[fi][fj][j];
                if constexpr (DO_RES) v += res[rbase + fj * 16];
                if constexpr (W_F32) outf[rbase + fj * 16] = v;
                if constexpr (W_BF) outb[rbase + fj * 16] = f2b(v);
            }
        }
}

// ---------------------------------------------------------------------------
// Ksum partials: kspart[b][ch][0][c] = sum_{l in chunk} sn_l*K[l,c]; [1]=cs
__global__ __launch_bounds__(256) void ksum_kernel(
    const ushort* __restrict__ Kmat, const float* __restrict__ snc,
    float* __restrict__ kspart)
{
    int ch = blockIdx.x, b = blockIdx.y;
    int c = threadIdx.x;
    int l0 = ch * 512;
    float as = 0.0f, ac = 0.0f;
    for (int i = 0; i < 512; ++i) {
        float k = b2f(Kmat[(size_t)(b * LL + l0 + i) * CDIM + c]);
        as += k * snc[(l0 + i) * 2];
        ac += k * snc[(l0 + i) * 2 + 1];
    }
    kspart[((size_t)(b * 8 + ch) * 2 + 0) * 256 + c] = as;
    kspart[((size_t)(b * 8 + ch) * 2 + 1) * 256 + c] = ac;
}

// ---------------------------------------------------------------------------
// cosFormer stage 1: partial KVs/KVc (32x32) per (b,h,chunk). Stride 2048.
__global__ __launch_bounds__(256) void kv_kernel(
    const ushort* __restrict__ Kmat, const ushort* __restrict__ Vmat,
    const float* __restrict__ snc, float* __restrict__ kvpart)
{
    __shared__ float Kt[64][36];
    __shared__ float Vt[64][36];
    __shared__ float sns[64], css[64];
    int chunk = blockIdx.x;
    int bh = blockIdx.y;
    int b = bh >> 3, h = bh & 7;
    int tid = threadIdx.x;
    int m = tid & 31;
    int d0 = (tid >> 5) * 4;
    float accs[4] = {}, accc[4] = {};
    int l0chunk = chunk * 512;
    int lrow = tid >> 2;             // 0..63
    int lcol = (tid & 3) * 8;        // 0,8,16,24
    for (int sub = 0; sub < 8; ++sub) {
        int l0 = l0chunk + sub * 64;
        {
            size_t gbase = (size_t)(b * LL + l0 + lrow) * CDIM + h * 32 + lcol;
            uint4 kr = *(const uint4*)&Kmat[gbase];
            uint4 vr = *(const uint4*)&Vmat[gbase];
            float* kd = &Kt[lrow][lcol];
            float* vd = &Vt[lrow][lcol];
            kd[0] = b2f((ushort)(kr.x & 0xffff)); kd[1] = b2f((ushort)(kr.x >> 16));
            kd[2] = b2f((ushort)(kr.y & 0xffff)); kd[3] = b2f((ushort)(kr.y >> 16));
            kd[4] = b2f((ushort)(kr.z & 0xffff)); kd[5] = b2f((ushort)(kr.z >> 16));
            kd[6] = b2f((ushort)(kr.w & 0xffff)); kd[7] = b2f((ushort)(kr.w >> 16));
            vd[0] = b2f((ushort)(vr.x & 0xffff)); vd[1] = b2f((ushort)(vr.x >> 16));
            vd[2] = b2f((ushort)(vr.y & 0xffff)); vd[3] = b2f((ushort)(vr.y >> 16));
            vd[4] = b2f((ushort)(vr.z & 0xffff)); vd[5] = b2f((ushort)(vr.z >> 16));
            vd[6] = b2f((ushort)(vr.w & 0xffff)); vd[7] = b2f((ushort)(vr.w >> 16));
        }
        if (tid < 64) { sns[tid] = snc[(l0 + tid) * 2]; css[tid] = snc[(l0 + tid) * 2 + 1]; }
        __syncthreads();
        #pragma unroll 4
        for (int lt = 0; lt < 64; ++lt) {
            float v = Vt[lt][m];
            float vs = v * sns[lt];
            float vc = v * css[lt];
            float4 kd4 = *(const float4*)&Kt[lt][d0];
            accs[0] += kd4.x * vs; accc[0] += kd4.x * vc;
            accs[1] += kd4.y * vs; accc[1] += kd4.y * vc;
            accs[2] += kd4.z * vs; accc[2] += kd4.z * vc;
            accs[3] += kd4.w * vs; accc[3] += kd4.w * vc;
        }
        __syncthreads();
    }
    size_t base = (size_t)(bh * 8 + chunk) * 2048;
    #pragma unroll
    for (int i2 = 0; i2 < 4; ++i2) {
        kvpart[base + (d0 + i2) * 32 + m] = accs[i2];
        kvpart[base + 1024 + (d0 + i2) * 32 + m] = accc[i2];
    }
}

// ---------------------------------------------------------------------------
// Reduce chunk partials into per-(b,h) MFMA B-image, hi/lo bf16 split.
// 160 rows x 32 k: rows 0-15 KVs[:,0:16]^T, 16-31 KVs[:,16:32]^T, 32-63 KVc same,
// 64: n=64 Ksum_s, n=65 Ksum_c, rest 0; rows 80-159 = lo residuals.
__global__ __launch_bounds__(256) void kvred_kernel(
    const float* __restrict__ kvpart, const float* __restrict__ kspart,
    ushort* __restrict__ Bimg)
{
    int bh = blockIdx.x;
    int b = bh >> 3, h = bh & 7;
    int tid = threadIdx.x;
    for (int e = tid; e < 2560; e += 256) {
        int n = e >> 5;      // 0..79
        int k = e & 31;      // d
        int t = n >> 4, col = n & 15;
        float v = 0.0f;
        if (t < 4) {
            int off = (t >= 2 ? 1024 : 0) + k * 32 + (t & 1) * 16 + col;
            #pragma unroll
            for (int ch = 0; ch < 8; ++ch)
                v += kvpart[(size_t)(bh * 8 + ch) * 2048 + off];
        } else if (col < 2) {
            #pragma unroll
            for (int ch = 0; ch < 8; ++ch)
                v += kspart[((size_t)(b * 8 + ch) * 2 + col) * 256 + h * 32 + k];
        }
        ushort hi = f2b(v);
        ushort lo = f2b(v - b2f(hi));
        Bimg[(size_t)bh * 5120 + n * 32 + k] = hi;
        Bimg[(size_t)bh * 5120 + (80 + n) * 32 + k] = lo;
    }
}

// ---------------------------------------------------------------------------
// attn via MFMA: per (ltile, h, b): 256 rows. attn = (sn*Q@KVs + cs*Q@KVc) * Z,
// Z = 1/max(sn*Q.Ksum_s + cs*Q.Ksum_c, eps) from B-cols 64/65.
__global__ __launch_bounds__(256, 2) void attn_mfma(
    const ushort* __restrict__ Qmat, const ushort* __restrict__ Bimg,
    const float* __restrict__ snc, ushort* __restrict__ attnOut)
{
    __shared__ ushort Bs[5120];
    int ltile = blockIdx.x, h = blockIdx.y, b = blockIdx.z;
    int bh = b * 8 + h;
    int tid = threadIdx.x;
    int lane = tid & 63;
    int wv = tid >> 6;

    for (int e = tid; e < 640; e += 256)
        *(uint4*)&Bs[e * 8] = *(const uint4*)&Bimg[(size_t)bh * 5120 + e * 8];
    __syncthreads();

    // B fragments: 10 tiles (5 hi + 5 lo)
    bf16x8 bfr[10];
    #pragma unroll
    for (int tt = 0; tt < 10; ++tt) {
        int row = (tt < 5 ? tt * 16 : 80 + (tt - 5) * 16) + (lane & 15);
        bfr[tt] = *(const bf16x8*)&Bs[row * 32 + (lane >> 4) * 8];
    }
    // A fragments: Q rows from global
    int lbase = ltile * 256 + wv * 64;
    bf16x8 af[4];
    #pragma unroll
    for (int fi = 0; fi < 4; ++fi) {
        int l = lbase + fi * 16 + (lane & 15);
        af[fi] = *(const bf16x8*)&Qmat[(size_t)(b * LL + l) * CDIM + h * 32 + (lane >> 4) * 8];
    }
    f32x4 acc[4][5] = {};
    #pragma unroll
    for (int fi = 0; fi < 4; ++fi)
        #pragma unroll
        for (int t = 0; t < 5; ++t) {
            acc[fi][t] = __builtin_amdgcn_mfma_f32_16x16x32_bf16(af[fi], bfr[t], acc[fi][t], 0, 0, 0);
            acc[fi][t] = __builtin_amdgcn_mfma_f32_16x16x32_bf16(af[fi], bfr[t + 5], acc[fi][t], 0, 0, 0);
        }

    int zlane = lane & 48;
    int cl = lane & 15;
    #pragma unroll
    for (int fi = 0; fi < 4; ++fi) {
        #pragma unroll
        for (int j = 0; j < 4; ++j) {
            float zraw = acc[fi][4][j];
            float zs = __shfl(zraw, zlane, 64);
            float zc = __shfl(zraw, zlane | 1, 64);
            int l = lbase + fi * 16 + ((lane >> 4) & 3) * 4 + j;
            float sn = snc[l * 2], cs = snc[l * 2 + 1];
            float den = sn * zs + cs * zc;
            float Z = 1.0f / fmaxf(den, 1e-6f);
            float v0 = (sn * acc[fi][0][j] + cs * acc[fi][2][j]) * Z;
            float v1 = (sn * acc[fi][1][j] + cs * acc[fi][3][j]) * Z;
            size_t ob = (size_t)(b * LL + l) * CDIM + h * 32 + cl;
            attnOut[ob] = f2b(v0);
            attnOut[ob + 16] = f2b(v1);
        }
    }
}

// ---------------------------------------------------------------------------
// ffeat f32 (b,L,256) -> (b,c,64,64) -> bilinear x2 * a3 -> out
__global__ __launch_bounds__(256) void resize_mul_kernel(
    const float* __restrict__ ffeat, const float* __restrict__ a3, float* __restrict__ out)
{
    __shared__ float ft[3][64][65];
    int k = blockIdx.x, ct = blockIdx.y, b = blockIdx.z;
    int tid = threadIdx.x;
    for (int it = 0; it < 48; ++it) {
        int e = it * 256 + tid;
        int cc = e & 63;
        int xs = (e >> 6) & 63;
        int ys = e >> 12;
        int ysrc = min(max(k - 1 + ys, 0), 63);
        ft[ys][cc][xs] = ffeat[(size_t)(b * LL + ysrc * 64 + xs) * CDIM + ct * 64 + cc];
    }
    __syncthreads();
    int x = tid & 127;
    int half = tid >> 7;
    int y = 2 * k + half;
    int ysA, ysB; float wyA, wyB;
    if (half == 0) { ysA = 0; ysB = 1; wyA = 0.25f; wyB = 0.75f; }
    else           { ysA = 1; ysB = 2; wyA = 0.75f; wyB = 0.25f; }
    int x0; float wx1;
    if ((x & 1) == 0) { x0 = x / 2 - 1; wx1 = 0.75f; }
    else              { x0 = x / 2;     wx1 = 0.25f; }
    int x0c = max(x0, 0);
    int x1c = min(x0 + 1, 63);
    float wx0 = 1.0f - wx1;
    for (int cc = 0; cc < 64; ++cc) {
        float rA = wx0 * ft[ysA][cc][x0c] + wx1 * ft[ysA][cc][x1c];
        float rB = wx0 * ft[ysB][cc][x0c] + wx1 * ft[ysB][cc][x1c];
        float val = wyA * rA + wyB * rB;
        size_t oidx = ((size_t)(b * 256 + ct * 64 + cc) * 128 + y) * 128 + x;
        out[oidx] = val * a3[oidx];
    }
}

// ---------------------------------------------------------------------------
extern "C" void kernel_launch(void* const* d_in, const int* in_sizes, int n_in,
                              void* d_out, int out_size, void* d_ws, size_t ws_size,
                              hipStream_t stream)
{
    const float* a3     = (const float*)d_in[0];
    const float* a4     = (const float*)d_in[1];
    const float* q_w    = (const float*)d_in[2];
    const float* q_b    = (const float*)d_in[3];
    const float* q_ln_g = (const float*)d_in[4];
    const float* q_ln_b = (const float*)d_in[5];
    const float* k_w    = (const float*)d_in[6];
    const float* k_b    = (const float*)d_in[7];
    const float* k_ln_g = (const float*)d_in[8];
    const float* k_ln_b = (const float*)d_in[9];
    const float* v_w    = (const float*)d_in[10];
    const float* v_b    = (const float*)d_in[11];
    const float* out_w  = (const float*)d_in[12];
    const float* out_b  = (const float*)d_in[13];
    const float* lin1_w = (const float*)d_in[14];
    const float* lin1_b = (const float*)d_in[15];
    const float* lin2_w = (const float*)d_in[16];
    const float* lin2_b = (const float*)d_in[17];
    const float* n1_g   = (const float*)d_in[18];
    const float* n1_b   = (const float*)d_in[19];
    const float* n2_g   = (const float*)d_in[20];
    const float* n2_b   = (const float*)d_in[21];
    float* out = (float*)d_out;
    char* base = (char*)d_ws;

    const size_t MiB = 1024 * 1024;
    float*  pos      = (float*)(base);                       // 4 MiB
    float*  snc      = (float*)(base + 4 * MiB);             // 32 KiB
    ushort* wqT      = (ushort*)(base + 4 * MiB + 64 * 1024);
    ushort* wkT      = wqT + 256 * 256;
    ushort* wvT      = wkT + 256 * 256;
    ushort* woT      = wvT + 256 * 256;
    ushort* w1T      = woT + 256 * 256;       // [1024][256]
    ushort* w2T      = w1T + 1024 * 256;      // [256][1024]
    float*  residual = (float*)(base + 6 * MiB);             // 64 MiB (ffeat reuses)
    ushort* x3b      = (ushort*)(base + 70 * MiB);           // 32 MiB (attnb reuses)
    ushort* x4b      = (ushort*)(base + 102 * MiB);          // 32 MiB (res2b reuses)
    ushort* Qb       = (ushort*)(base + 134 * MiB);
    ushort* Kb       = (ushort*)(base + 166 * MiB);
    ushort* Vb       = (ushort*)(base + 198 * MiB);
    float*  kvp      = (float*)(base + 230 * MiB);           // 8 MiB
    float*  kspart   = (float*)(base + 238 * MiB);           // 256 KiB
    ushort* Bimg     = (ushort*)(base + 239 * MiB);          // 1.25 MiB
    float*  res2f    = (float*)(base + 241 * MiB);           // 64 MiB
    ushort* h1b      = (ushort*)(base + 305 * MiB);          // 128 MiB -> 433 MiB
    ushort* attnb    = x3b;
    ushort* res2b    = x4b;
    float*  ffeat    = residual;

    pos_kernel<<<LL, 256, 0, stream>>>(pos, snc);
    wt_kernel<<<dim3(8, 8), 256, 0, stream>>>(q_w, wqT, 256, 256);
    wt_kernel<<<dim3(8, 8), 256, 0, stream>>>(k_w, wkT, 256, 256);
    wt_kernel<<<dim3(8, 8), 256, 0, stream>>>(v_w, wvT, 256, 256);
    wt_kernel<<<dim3(8, 8), 256, 0, stream>>>(out_w, woT, 256, 256);
    wt_kernel<<<dim3(8, 32), 256, 0, stream>>>(lin1_w, w1T, 256, 1024);
    wt_kernel<<<dim3(32, 8), 256, 0, stream>>>(lin2_w, w2T, 1024, 256);

    pool_x3_kernel<<<dim3(64, 4, 16), 256, 0, stream>>>(a3, residual, x3b, pos);
    x4_kernel<<<dim3(64, 4, 16), 256, 0, stream>>>(a4, x4b, pos);

    gemm_mfma<true, true, false, false, true, false><<<dim3(NROWS / 64, 1), 256, 0, stream>>>(
        x3b, wqT, q_b, q_ln_g, q_ln_b, nullptr, Qb, nullptr, 256, 256);
    gemm_mfma<true, true, false, false, true, false><<<dim3(NROWS / 64, 1), 256, 0, stream>>>(
        x4b, wkT, k_b, k_ln_g, k_ln_b, nullptr, Kb, nullptr, 256, 256);
    gemm_mfma<false, false, false, false, true, false><<<dim3(NROWS / 64, 1), 256, 0, stream>>>(
        x4b, wvT, v_b, nullptr, nullptr, nullptr, Vb, nullptr, 256, 256);

    ksum_kernel<<<dim3(8, 16), 256, 0, stream>>>(Kb, snc, kspart);
    kv_kernel<<<dim3(8, 128), 256, 0, stream>>>(Kb, Vb, snc, kvp);
    kvred_kernel<<<128, 256, 0, stream>>>(kvp, kspart, Bimg);
    attn_mfma<<<dim3(16, 8, 16), 256, 0, stream>>>(Qb, Bimg, snc, attnb);

    gemm_mfma<true, false, false, true, true, true><<<dim3(NROWS / 64, 1), 256, 0, stream>>>(
        attnb, woT, out_b, n1_g, n1_b, residual, res2b, res2f, 256, 256);
    gemm_mfma<false, false, true, false, true, false><<<dim3(NROWS / 64, 4), 256, 0, stream>>>(
        res2b, w1T, lin1_b, nullptr, nullptr, nullptr, h1b, nullptr, 256, 1024);
    gemm_mfma<true, false, false, true, false, true><<<dim3(NROWS / 64, 1), 256, 0, stream>>>(
        h1b, w2T, lin2_b, n2_g, n2_b, res2f, nullptr, ffeat, 1024, 256);

    resize_mul_kernel<<<dim3(64, 4, 16), 256, 0, stream>>>(ffeat, a3, out);
}

// Round 4
// 605.539 us; speedup vs baseline: 3.0712x; 1.0809x over previous
//
#include <hip/hip_runtime.h>
#include <hip/hip_bf16.h>
#include <math.h>

#define HEADS 8
#define LL 4096
#define CDIM 256
#define BATCH 16
#define NROWS (BATCH*LL)

typedef __attribute__((ext_vector_type(8))) __bf16 bf16x8;
typedef __attribute__((ext_vector_type(4))) float f32x4;

__device__ inline float b2f(ushort u) {
    union { unsigned u; float f; } v; v.u = ((unsigned)u) << 16; return v.f;
}
__device__ inline ushort f2b(float f) {
    union { float f; unsigned u; } v; v.f = f;
    unsigned r = (v.u + 0x7FFF + ((v.u >> 16) & 1)) >> 16;
    return (ushort)r;
}
__device__ inline void gload16(const void* g, void* l) {
    __builtin_amdgcn_global_load_lds(
        (const __attribute__((address_space(1))) unsigned int*)g,
        (__attribute__((address_space(3))) unsigned int*)l, 16, 0, 0);
}

// ---------------------------------------------------------------------------
// Fused prep: pos table + snc table (blocks 0..1023) and 6 weight transposes
// (blocks 1024..1791). wt: W[K][N] f32 -> Wt[N][K] bf16, 32x32 tiles.
__global__ __launch_bounds__(256) void prep_kernel(
    float* __restrict__ pos, float* __restrict__ snc,
    const float* __restrict__ q_w, const float* __restrict__ k_w,
    const float* __restrict__ v_w, const float* __restrict__ o_w,
    const float* __restrict__ w1, const float* __restrict__ w2,
    ushort* __restrict__ wqT, ushort* __restrict__ wkT,
    ushort* __restrict__ wvT, ushort* __restrict__ woT,
    ushort* __restrict__ w1T, ushort* __restrict__ w2T)
{
    __shared__ float t[32][33];
    int bid = blockIdx.x;
    int tid = threadIdx.x;
    if (bid < 1024) {
        int c = tid;
        int k = c & 63;
        float omega = expf(-(float)k * (9.210340371976184f / 64.0f));  // ln(10000)/64
        #pragma unroll
        for (int i = 0; i < 4; ++i) {
            int l = bid * 4 + i;
            int y = l >> 6, x = l & 63;
            float coord = (c < 128) ? (float)y : (float)x;
            float ang = coord * omega;
            float val = ((c & 127) < 64) ? sinf(ang) : cosf(ang);
            pos[l * CDIM + c] = val;
            if (c < 2) {
                float wi = 1.5707963267948966f * (float)(l + 1) / (float)LL;
                snc[l * 2 + c] = (c == 0) ? sinf(wi) : cosf(wi);
            }
        }
        return;
    }
    int id = bid - 1024;
    const float* W; ushort* Wt; int K, N, kb, nb;
    if (id < 64)       { W = q_w; Wt = wqT; K = 256;  N = 256;  kb = (id & 7) * 32;  nb = (id >> 3) * 32; }
    else if (id < 128) { id -= 64;  W = k_w; Wt = wkT; K = 256;  N = 256;  kb = (id & 7) * 32;  nb = (id >> 3) * 32; }
    else if (id < 192) { id -= 128; W = v_w; Wt = wvT; K = 256;  N = 256;  kb = (id & 7) * 32;  nb = (id >> 3) * 32; }
    else if (id < 256) { id -= 192; W = o_w; Wt = woT; K = 256;  N = 256;  kb = (id & 7) * 32;  nb = (id >> 3) * 32; }
    else if (id < 512) { id -= 256; W = w1;  Wt = w1T; K = 256;  N = 1024; kb = (id & 7) * 32;  nb = (id >> 3) * 32; }
    else               { id -= 512; W = w2;  Wt = w2T; K = 1024; N = 256;  kb = (id & 31) * 32; nb = (id >> 5) * 32; }
    int x = tid & 31, y = tid >> 5;
    #pragma unroll
    for (int i = 0; i < 4; ++i)
        t[y + i * 8][x] = W[(size_t)(kb + y + i * 8) * N + nb + x];
    __syncthreads();
    #pragma unroll
    for (int i = 0; i < 4; ++i) {
        int n = y + i * 8;
        Wt[(size_t)(nb + n) * K + kb + x] = f2b(t[x][n]);
    }
}

// ---------------------------------------------------------------------------
// a3 (b,256,128,128) --avgpool2--> residual bf16 (b,L,256), x3 bf16 = residual + pos
__global__ __launch_bounds__(256) void pool_x3_kernel(
    const float* __restrict__ a3, ushort* __restrict__ residual,
    ushort* __restrict__ x3b, const float* __restrict__ pos)
{
    __shared__ float raw[64][128];
    __shared__ float pooled[64][65];
    int i = blockIdx.x, ct = blockIdx.y, b = blockIdx.z;
    int tid = threadIdx.x;
    #pragma unroll
    for (int it = 0; it < 8; ++it) {
        int lin = (it * 256 + tid) * 4;
        int x = lin & 127;
        int cc = lin >> 7;
        size_t base = ((size_t)(b * 256 + ct * 64 + cc) * 128 + 2 * i) * 128 + x;
        float4 v0 = *(const float4*)&a3[base];
        float4 v1 = *(const float4*)&a3[base + 128];
        float4 s = make_float4(v0.x + v1.x, v0.y + v1.y, v0.z + v1.z, v0.w + v1.w);
        *(float4*)&raw[cc][x] = s;
    }
    __syncthreads();
    #pragma unroll
    for (int it = 0; it < 16; ++it) {
        int idx = it * 256 + tid;
        int j = idx & 63, cc = idx >> 6;
        pooled[cc][j] = 0.25f * (raw[cc][2 * j] + raw[cc][2 * j + 1]);
    }
    __syncthreads();
    #pragma unroll
    for (int it = 0; it < 16; ++it) {
        int cc = tid & 63;
        int jj = (tid >> 6) + it * 4;
        float val = pooled[cc][jj];
        int l = i * 64 + jj;
        int c = ct * 64 + cc;
        size_t o = (size_t)(b * LL + l) * CDIM + c;
        residual[o] = f2b(val);
        x3b[o] = f2b(val + pos[l * CDIM + c]);
    }
}

// ---------------------------------------------------------------------------
// a4 (b,256,64,64) --transpose--> x4 bf16 (b,L,256) + pos
__global__ __launch_bounds__(256) void x4_kernel(
    const float* __restrict__ a4, ushort* __restrict__ x4b, const float* __restrict__ pos)
{
    __shared__ float t2[64][65];
    int y = blockIdx.x, ct = blockIdx.y, b = blockIdx.z, tid = threadIdx.x;
    #pragma unroll
    for (int it = 0; it < 16; ++it) {
        int idx = it * 256 + tid;
        int x = idx & 63, cc = idx >> 6;
        t2[cc][x] = a4[((size_t)(b * 256 + ct * 64 + cc) * 64 + y) * 64 + x];
    }
    __syncthreads();
    #pragma unroll
    for (int it = 0; it < 16; ++it) {
        int cc = tid & 63;
        int xx = (tid >> 6) + it * 4;
        int l = y * 64 + xx, c = ct * 64 + cc;
        x4b[(size_t)(b * LL + l) * CDIM + c] = f2b(t2[cc][xx] + pos[l * CDIM + c]);
    }
}

// ---------------------------------------------------------------------------
// MFMA GEMM: out = epilogue(A @ Wt^T + bias) [+ res]; A: N x K bf16, Wt: colsTot x K bf16.
// Block: 128 rows x 256 cols, 512 threads = 8 waves (2 row x 4 col), 64x64/wave.
template<bool DO_LN, bool DO_RELU, bool DO_GELU, bool DO_RES>
__global__ __launch_bounds__(512, 2) void gemm_mfma(
    const ushort* __restrict__ A, const ushort* __restrict__ Wt,
    const float* __restrict__ bias, const float* __restrict__ gam_,
    const float* __restrict__ bet_, const ushort* __restrict__ res,
    ushort* __restrict__ outb, int K, int colsTot)
{
    __shared__ ushort As[128 * 32];    // 8 KB, [row][32k] in 16B swizzled slots
    __shared__ ushort Bs[256 * 32];    // 16 KB
    __shared__ float redS[128][4];
    __shared__ float redQ[128][4];
    __shared__ float2 mustd[128];

    const int tid = threadIdx.x;
    const int lane = tid & 63;
    const int wv = tid >> 6;     // 0..7
    const int wr = wv >> 2;      // 0..1 (row half)
    const int wc = wv & 3;       // 0..3 (col quarter)
    const int wvu = __builtin_amdgcn_readfirstlane(wv);
    const int row0 = blockIdx.x * 128;
    const int cb = blockIdx.y * 256;

    const int sr = tid >> 2;                      // 0..127
    const int sg = (tid & 3) ^ ((sr >> 1) & 3);   // swizzled source k-group
    const ushort* aSrc = A + (size_t)(row0 + sr) * K + sg * 8;
    const ushort* bSrc0 = Wt + (size_t)(cb + sr) * K + sg * 8;
    const ushort* bSrc1 = Wt + (size_t)(cb + 128 + sr) * K + sg * 8;

    const int frSlot = (lane >> 4) ^ (((lane & 15) >> 1) & 3);

    f32x4 acc[4][4] = {};
    for (int kb = 0; kb < K; kb += 32) {
        gload16(aSrc + kb, (char*)&As[0] + wvu * 1024);
        gload16(bSrc0 + kb, (char*)&Bs[0] + wvu * 1024);
        gload16(bSrc1 + kb, (char*)&Bs[0] + 8192 + wvu * 1024);
        __syncthreads();

        bf16x8 af[4], bfr[4];
        #pragma unroll
        for (int f = 0; f < 4; ++f) {
            int r = wr * 64 + f * 16 + (lane & 15);
            af[f] = *(const bf16x8*)&As[r * 32 + frSlot * 8];
            int c = wc * 64 + f * 16 + (lane & 15);
            bfr[f] = *(const bf16x8*)&Bs[c * 32 + frSlot * 8];
        }
        #pragma unroll
        for (int fi = 0; fi < 4; ++fi)
            #pragma unroll
            for (int fj = 0; fj < 4; ++fj)
                acc[fi][fj] = __builtin_amdgcn_mfma_f32_16x16x32_bf16(
                    af[fi], bfr[fj], acc[fi][fj], 0, 0, 0);
        __syncthreads();
    }

    const int cl = lane & 15;
    const int rg = lane >> 4;    // 0..3
    float bia[4], gmv[4], btv[4];
    #pragma unroll
    for (int fj = 0; fj < 4; ++fj) {
        int col = cb + wc * 64 + fj * 16 + cl;
        bia[fj] = bias[col];
        if constexpr (DO_LN) { gmv[fj] = gam_[col]; btv[fj] = bet_[col]; }
    }
    #pragma unroll
    for (int fi = 0; fi < 4; ++fi)
        #pragma unroll
        for (int fj = 0; fj < 4; ++fj)
            #pragma unroll
            for (int j = 0; j < 4; ++j)
                acc[fi][fj][j] += bia[fj];

    if constexpr (DO_LN) {   // requires colsTot == 256, gridDim.y == 1
        #pragma unroll
        for (int fi = 0; fi < 4; ++fi)
            #pragma unroll
            for (int j = 0; j < 4; ++j) {
                float s = acc[fi][0][j] + acc[fi][1][j] + acc[fi][2][j] + acc[fi][3][j];
                float q = acc[fi][0][j] * acc[fi][0][j] + acc[fi][1][j] * acc[fi][1][j]
                        + acc[fi][2][j] * acc[fi][2][j] + acc[fi][3][j] * acc[fi][3][j];
                #pragma unroll
                for (int m = 1; m <= 8; m <<= 1) {
                    s += __shfl_xor(s, m, 64);
                    q += __shfl_xor(q, m, 64);
                }
                if (cl == 0) {
                    int tr = wr * 64 + fi * 16 + rg * 4 + j;
                    redS[tr][wc] = s; redQ[tr][wc] = q;
                }
            }
        __syncthreads();
        if (tid < 128) {
            float s = redS[tid][0] + redS[tid][1] + redS[tid][2] + redS[tid][3];
            float q = redQ[tid][0] + redQ[tid][1] + redQ[tid][2] + redQ[tid][3];
            float mu = s * (1.0f / 256.0f);
            float var = q * (1.0f / 256.0f) - mu * mu;
            mustd[tid] = make_float2(mu, rsqrtf(var + 1e-5f));
        }
        __syncthreads();
        #pragma unroll
        for (int fi = 0; fi < 4; ++fi)
            #pragma unroll
            for (int j = 0; j < 4; ++j) {
                float2 ms = mustd[wr * 64 + fi * 16 + rg * 4 + j];
                #pragma unroll
                for (int fj = 0; fj < 4; ++fj)
                    acc[fi][fj][j] = (acc[fi][fj][j] - ms.x) * ms.y * gmv[fj] + btv[fj];
            }
    }
    if constexpr (DO_RELU) {
        #pragma unroll
        for (int fi = 0; fi < 4; ++fi)
            #pragma unroll
            for (int fj = 0; fj < 4; ++fj)
                #pragma unroll
                for (int j = 0; j < 4; ++j)
                    acc[fi][fj][j] = fmaxf(acc[fi][fj][j], 0.0f);
    }
    if constexpr (DO_GELU) {
        #pragma unroll
        for (int fi = 0; fi < 4; ++fi)
            #pragma unroll
            for (int fj = 0; fj < 4; ++fj)
                #pragma unroll
                for (int j = 0; j < 4; ++j) {
                    float v = acc[fi][fj][j];
                    acc[fi][fj][j] = 0.5f * v * (1.0f + erff(v * 0.7071067811865476f));
                }
    }
    #pragma unroll
    for (int fi = 0; fi < 4; ++fi)
        #pragma unroll
        for (int j = 0; j < 4; ++j) {
            size_t row = row0 + wr * 64 + fi * 16 + rg * 4 + j;
            size_t rbase = row * (size_t)colsTot + cb + wc * 64 + cl;
            #pragma unroll
            for (int fj = 0; fj < 4; ++fj) {
                float v = acc[fi][fj][j];
                if constexpr (DO_RES) v += b2f(res[rbase + fj * 16]);
                outb[rbase + fj * 16] = f2b(v);
            }
        }
}

// ---------------------------------------------------------------------------
// Ksum partials: kspart[b][ch][0][c] = sum_{l in chunk} sn_l*K[l,c]; [1]=cs
__global__ __launch_bounds__(256) void ksum_kernel(
    const ushort* __restrict__ Kmat, const float* __restrict__ snc,
    float* __restrict__ kspart)
{
    int ch = blockIdx.x, b = blockIdx.y;
    int c = threadIdx.x;
    int l0 = ch * 512;
    float as = 0.0f, ac = 0.0f;
    for (int i = 0; i < 512; ++i) {
        float k = b2f(Kmat[(size_t)(b * LL + l0 + i) * CDIM + c]);
        as += k * snc[(l0 + i) * 2];
        ac += k * snc[(l0 + i) * 2 + 1];
    }
    kspart[((size_t)(b * 8 + ch) * 2 + 0) * 256 + c] = as;
    kspart[((size_t)(b * 8 + ch) * 2 + 1) * 256 + c] = ac;
}

// ---------------------------------------------------------------------------
// cosFormer stage 1: partial KVs/KVc (32x32) per (b,h,chunk). Stride 2048.
__global__ __launch_bounds__(256) void kv_kernel(
    const ushort* __restrict__ Kmat, const ushort* __restrict__ Vmat,
    const float* __restrict__ snc, float* __restrict__ kvpart)
{
    __shared__ float Kt[64][36];
    __shared__ float Vt[64][36];
    __shared__ float sns[64], css[64];
    int chunk = blockIdx.x;
    int bh = blockIdx.y;
    int b = bh >> 3, h = bh & 7;
    int tid = threadIdx.x;
    int m = tid & 31;
    int d0 = (tid >> 5) * 4;
    float accs[4] = {}, accc[4] = {};
    int l0chunk = chunk * 512;
    int lrow = tid >> 2;
    int lcol = (tid & 3) * 8;
    for (int sub = 0; sub < 8; ++sub) {
        int l0 = l0chunk + sub * 64;
        {
            size_t gbase = (size_t)(b * LL + l0 + lrow) * CDIM + h * 32 + lcol;
            uint4 kr = *(const uint4*)&Kmat[gbase];
            uint4 vr = *(const uint4*)&Vmat[gbase];
            float* kd = &Kt[lrow][lcol];
            float* vd = &Vt[lrow][lcol];
            kd[0] = b2f((ushort)(kr.x & 0xffff)); kd[1] = b2f((ushort)(kr.x >> 16));
            kd[2] = b2f((ushort)(kr.y & 0xffff)); kd[3] = b2f((ushort)(kr.y >> 16));
            kd[4] = b2f((ushort)(kr.z & 0xffff)); kd[5] = b2f((ushort)(kr.z >> 16));
            kd[6] = b2f((ushort)(kr.w & 0xffff)); kd[7] = b2f((ushort)(kr.w >> 16));
            vd[0] = b2f((ushort)(vr.x & 0xffff)); vd[1] = b2f((ushort)(vr.x >> 16));
            vd[2] = b2f((ushort)(vr.y & 0xffff)); vd[3] = b2f((ushort)(vr.y >> 16));
            vd[4] = b2f((ushort)(vr.z & 0xffff)); vd[5] = b2f((ushort)(vr.z >> 16));
            vd[6] = b2f((ushort)(vr.w & 0xffff)); vd[7] = b2f((ushort)(vr.w >> 16));
        }
        if (tid < 64) { sns[tid] = snc[(l0 + tid) * 2]; css[tid] = snc[(l0 + tid) * 2 + 1]; }
        __syncthreads();
        #pragma unroll 4
        for (int lt = 0; lt < 64; ++lt) {
            float v = Vt[lt][m];
            float vs = v * sns[lt];
            float vc = v * css[lt];
            float4 kd4 = *(const float4*)&Kt[lt][d0];
            accs[0] += kd4.x * vs; accc[0] += kd4.x * vc;
            accs[1] += kd4.y * vs; accc[1] += kd4.y * vc;
            accs[2] += kd4.z * vs; accc[2] += kd4.z * vc;
            accs[3] += kd4.w * vs; accc[3] += kd4.w * vc;
        }
        __syncthreads();
    }
    size_t base = (size_t)(bh * 8 + chunk) * 2048;
    #pragma unroll
    for (int i2 = 0; i2 < 4; ++i2) {
        kvpart[base + (d0 + i2) * 32 + m] = accs[i2];
        kvpart[base + 1024 + (d0 + i2) * 32 + m] = accc[i2];
    }
}

// ---------------------------------------------------------------------------
// Reduce chunk partials into per-(b,h) MFMA B-image, hi/lo bf16 split.
__global__ __launch_bounds__(256) void kvred_kernel(
    const float* __restrict__ kvpart, const float* __restrict__ kspart,
    ushort* __restrict__ Bimg)
{
    int bh = blockIdx.x;
    int b = bh >> 3, h = bh & 7;
    int tid = threadIdx.x;
    for (int e = tid; e < 2560; e += 256) {
        int n = e >> 5;
        int k = e & 31;
        int t = n >> 4, col = n & 15;
        float v = 0.0f;
        if (t < 4) {
            int off = (t >= 2 ? 1024 : 0) + k * 32 + (t & 1) * 16 + col;
            #pragma unroll
            for (int ch = 0; ch < 8; ++ch)
                v += kvpart[(size_t)(bh * 8 + ch) * 2048 + off];
        } else if (col < 2) {
            #pragma unroll
            for (int ch = 0; ch < 8; ++ch)
                v += kspart[((size_t)(b * 8 + ch) * 2 + col) * 256 + h * 32 + k];
        }
        ushort hi = f2b(v);
        ushort lo = f2b(v - b2f(hi));
        Bimg[(size_t)bh * 5120 + n * 32 + k] = hi;
        Bimg[(size_t)bh * 5120 + (80 + n) * 32 + k] = lo;
    }
}

// ---------------------------------------------------------------------------
// attn via MFMA: per (ltile, h, b): 256 rows.
__global__ __launch_bounds__(256, 2) void attn_mfma(
    const ushort* __restrict__ Qmat, const ushort* __restrict__ Bimg,
    const float* __restrict__ snc, ushort* __restrict__ attnOut)
{
    __shared__ ushort Bs[5120];
    int ltile = blockIdx.x, h = blockIdx.y, b = blockIdx.z;
    int bh = b * 8 + h;
    int tid = threadIdx.x;
    int lane = tid & 63;
    int wv = tid >> 6;

    for (int e = tid; e < 640; e += 256)
        *(uint4*)&Bs[e * 8] = *(const uint4*)&Bimg[(size_t)bh * 5120 + e * 8];
    __syncthreads();

    bf16x8 bfr[10];
    #pragma unroll
    for (int tt = 0; tt < 10; ++tt) {
        int row = (tt < 5 ? tt * 16 : 80 + (tt - 5) * 16) + (lane & 15);
        bfr[tt] = *(const bf16x8*)&Bs[row * 32 + (lane >> 4) * 8];
    }
    int lbase = ltile * 256 + wv * 64;
    bf16x8 af[4];
    #pragma unroll
    for (int fi = 0; fi < 4; ++fi) {
        int l = lbase + fi * 16 + (lane & 15);
        af[fi] = *(const bf16x8*)&Qmat[(size_t)(b * LL + l) * CDIM + h * 32 + (lane >> 4) * 8];
    }
    f32x4 acc[4][5] = {};
    #pragma unroll
    for (int fi = 0; fi < 4; ++fi)
        #pragma unroll
        for (int t = 0; t < 5; ++t) {
            acc[fi][t] = __builtin_amdgcn_mfma_f32_16x16x32_bf16(af[fi], bfr[t], acc[fi][t], 0, 0, 0);
            acc[fi][t] = __builtin_amdgcn_mfma_f32_16x16x32_bf16(af[fi], bfr[t + 5], acc[fi][t], 0, 0, 0);
        }

    int zlane = lane & 48;
    int cl = lane & 15;
    #pragma unroll
    for (int fi = 0; fi < 4; ++fi) {
        #pragma unroll
        for (int j = 0; j < 4; ++j) {
            float zraw = acc[fi][4][j];
            float zs = __shfl(zraw, zlane, 64);
            float zc = __shfl(zraw, zlane | 1, 64);
            int l = lbase + fi * 16 + ((lane >> 4) & 3) * 4 + j;
            float sn = snc[l * 2], cs = snc[l * 2 + 1];
            float den = sn * zs + cs * zc;
            float Z = 1.0f / fmaxf(den, 1e-6f);
            float v0 = (sn * acc[fi][0][j] + cs * acc[fi][2][j]) * Z;
            float v1 = (sn * acc[fi][1][j] + cs * acc[fi][3][j]) * Z;
            size_t ob = (size_t)(b * LL + l) * CDIM + h * 32 + cl;
            attnOut[ob] = f2b(v0);
            attnOut[ob + 16] = f2b(v1);
        }
    }
}

// ---------------------------------------------------------------------------
// ffeat bf16 (b,L,256) -> (b,c,64,64) -> bilinear x2 * a3 -> out f32
__global__ __launch_bounds__(256) void resize_mul_kernel(
    const ushort* __restrict__ ffeat, const float* __restrict__ a3, float* __restrict__ out)
{
    __shared__ float ft[3][64][65];
    int k = blockIdx.x, ct = blockIdx.y, b = blockIdx.z;
    int tid = threadIdx.x;
    for (int it = 0; it < 48; ++it) {
        int e = it * 256 + tid;
        int cc = e & 63;
        int xs = (e >> 6) & 63;
        int ys = e >> 12;
        int ysrc = min(max(k - 1 + ys, 0), 63);
        ft[ys][cc][xs] = b2f(ffeat[(size_t)(b * LL + ysrc * 64 + xs) * CDIM + ct * 64 + cc]);
    }
    __syncthreads();
    int x = tid & 127;
    int half = tid >> 7;
    int y = 2 * k + half;
    int ysA, ysB; float wyA, wyB;
    if (half == 0) { ysA = 0; ysB = 1; wyA = 0.25f; wyB = 0.75f; }
    else           { ysA = 1; ysB = 2; wyA = 0.75f; wyB = 0.25f; }
    int x0; float wx1;
    if ((x & 1) == 0) { x0 = x / 2 - 1; wx1 = 0.75f; }
    else              { x0 = x / 2;     wx1 = 0.25f; }
    int x0c = max(x0, 0);
    int x1c = min(x0 + 1, 63);
    float wx0 = 1.0f - wx1;
    for (int cc = 0; cc < 64; ++cc) {
        float rA = wx0 * ft[ysA][cc][x0c] + wx1 * ft[ysA][cc][x1c];
        float rB = wx0 * ft[ysB][cc][x0c] + wx1 * ft[ysB][cc][x1c];
        float val = wyA * rA + wyB * rB;
        size_t oidx = ((size_t)(b * 256 + ct * 64 + cc) * 128 + y) * 128 + x;
        out[oidx] = val * a3[oidx];
    }
}

// ---------------------------------------------------------------------------
extern "C" void kernel_launch(void* const* d_in, const int* in_sizes, int n_in,
                              void* d_out, int out_size, void* d_ws, size_t ws_size,
                              hipStream_t stream)
{
    const float* a3     = (const float*)d_in[0];
    const float* a4     = (const float*)d_in[1];
    const float* q_w    = (const float*)d_in[2];
    const float* q_b    = (const float*)d_in[3];
    const float* q_ln_g = (const float*)d_in[4];
    const float* q_ln_b = (const float*)d_in[5];
    const float* k_w    = (const float*)d_in[6];
    const float* k_b    = (const float*)d_in[7];
    const float* k_ln_g = (const float*)d_in[8];
    const float* k_ln_b = (const float*)d_in[9];
    const float* v_w    = (const float*)d_in[10];
    const float* v_b    = (const float*)d_in[11];
    const float* out_w  = (const float*)d_in[12];
    const float* out_b  = (const float*)d_in[13];
    const float* lin1_w = (const float*)d_in[14];
    const float* lin1_b = (const float*)d_in[15];
    const float* lin2_w = (const float*)d_in[16];
    const float* lin2_b = (const float*)d_in[17];
    const float* n1_g   = (const float*)d_in[18];
    const float* n1_b   = (const float*)d_in[19];
    const float* n2_g   = (const float*)d_in[20];
    const float* n2_b   = (const float*)d_in[21];
    float* out = (float*)d_out;
    char* base = (char*)d_ws;

    const size_t MiB = 1024 * 1024;
    float*  pos      = (float*)(base);                       // 4 MiB
    float*  snc      = (float*)(base + 4 * MiB);             // 32 KiB
    ushort* wqT      = (ushort*)(base + 4 * MiB + 64 * 1024);
    ushort* wkT      = wqT + 256 * 256;
    ushort* wvT      = wkT + 256 * 256;
    ushort* woT      = wvT + 256 * 256;
    ushort* w1T      = woT + 256 * 256;       // [1024][256]
    ushort* w2T      = w1T + 1024 * 256;      // [256][1024]
    ushort* residual = (ushort*)(base + 6 * MiB);            // 32 MiB (ffeat reuses)
    ushort* x3b      = (ushort*)(base + 38 * MiB);           // 32 MiB (attnb reuses)
    ushort* x4b      = (ushort*)(base + 70 * MiB);           // 32 MiB (res2b reuses)
    ushort* Qb       = (ushort*)(base + 102 * MiB);
    ushort* Kb       = (ushort*)(base + 134 * MiB);
    ushort* Vb       = (ushort*)(base + 166 * MiB);
    float*  kvp      = (float*)(base + 198 * MiB);           // 8 MiB
    float*  kspart   = (float*)(base + 206 * MiB);           // 256 KiB
    ushort* Bimg     = (ushort*)(base + 207 * MiB);          // 1.25 MiB
    ushort* h1b      = (ushort*)(base + 209 * MiB);          // 128 MiB -> 337 MiB
    ushort* attnb    = x3b;
    ushort* res2b    = x4b;
    ushort* ffeat    = residual;

    prep_kernel<<<1792, 256, 0, stream>>>(pos, snc, q_w, k_w, v_w, out_w, lin1_w, lin2_w,
                                          wqT, wkT, wvT, woT, w1T, w2T);
    pool_x3_kernel<<<dim3(64, 4, 16), 256, 0, stream>>>(a3, residual, x3b, pos);
    x4_kernel<<<dim3(64, 4, 16), 256, 0, stream>>>(a4, x4b, pos);

    gemm_mfma<true, true, false, false><<<dim3(NROWS / 128, 1), 512, 0, stream>>>(
        x3b, wqT, q_b, q_ln_g, q_ln_b, nullptr, Qb, 256, 256);
    gemm_mfma<true, true, false, false><<<dim3(NROWS / 128, 1), 512, 0, stream>>>(
        x4b, wkT, k_b, k_ln_g, k_ln_b, nullptr, Kb, 256, 256);
    gemm_mfma<false, false, false, false><<<dim3(NROWS / 128, 1), 512, 0, stream>>>(
        x4b, wvT, v_b, nullptr, nullptr, nullptr, Vb, 256, 256);

    ksum_kernel<<<dim3(8, 16), 256, 0, stream>>>(Kb, snc, kspart);
    kv_kernel<<<dim3(8, 128), 256, 0, stream>>>(Kb, Vb, snc, kvp);
    kvred_kernel<<<128, 256, 0, stream>>>(kvp, kspart, Bimg);
    attn_mfma<<<dim3(16, 8, 16), 256, 0, stream>>>(Qb, Bimg, snc, attnb);

    // out-proj + LN(n1) + residual -> res2 (bf16)
    gemm_mfma<true, false, false, true><<<dim3(NROWS / 128, 1), 512, 0, stream>>>(
        attnb, woT, out_b, n1_g, n1_b, residual, res2b, 256, 256);
    // MLP
    gemm_mfma<false, false, true, false><<<dim3(NROWS / 128, 4), 512, 0, stream>>>(
        res2b, w1T, lin1_b, nullptr, nullptr, nullptr, h1b, 256, 1024);
    gemm_mfma<true, false, false, true><<<dim3(NROWS / 128, 1), 512, 0, stream>>>(
        h1b, w2T, lin2_b, n2_g, n2_b, res2b, ffeat, 1024, 256);

    resize_mul_kernel<<<dim3(64, 4, 16), 256, 0, stream>>>(ffeat, a3, out);
}